// Round 11
// baseline (435.629 us; speedup 1.0000x reference)
//
#include <hip/hip_runtime.h>
#include <math.h>

#define HH 256
#define WW 256
#define BATCH 8
#define HWSZ 65536
#define BN_N 524288.0f  // BATCH*HWSZ

typedef __attribute__((ext_vector_type(8))) short short8;
typedef __attribute__((ext_vector_type(4))) float floatx4;

// round-half-up bf16 pack: 2 VALU ops, max err 0.5 ulp
__device__ __forceinline__ unsigned short f2bf(float f) {
  union { float f; unsigned int u; } v; v.f = f;
  return (unsigned short)((v.u + 0x8000u) >> 16);
}
// pack two fp32 -> bf16x2 (lo=a, hi=d): 5 VALU ops
__device__ __forceinline__ unsigned int pack2bf(float a, float d) {
  union { float f; unsigned int u; } va, vd; va.f = a; vd.f = d;
  return ((va.u + 0x8000u) >> 16) | ((vd.u + 0x8000u) & 0xffff0000u);
}
__device__ __forceinline__ float bf2f(unsigned short u) {
  union { unsigned int u; float f; } v; v.u = ((unsigned int)u) << 16;
  return v.f;
}

// ---- conv1 (grid y<8) + weight pre-swizzle for conv2/conv3 (y==8) ---------
__global__ __launch_bounds__(256) void conv1_prep(
    const float* __restrict__ in, const float* __restrict__ wgt,
    const float* __restrict__ bias, unsigned short* __restrict__ out,
    float* __restrict__ totals1,
    const float* __restrict__ w2, const float* __restrict__ w3,
    unsigned short* __restrict__ wf2, unsigned short* __restrict__ wf3)
{
  if (blockIdx.y == 8) {  // ---- prep path: 360 blocks cover 92160 elems ----
    int idx = blockIdx.x * 256 + threadIdx.x;
    if (idx < 18432) {  // conv2: CIN=32, COUT=64, KC=1, NG=4
      const int j = idx & 7;
      const int lane = (idx >> 3) & 63;
      int rest = idx >> 9;
      const int ng = rest % 4;
      const int tap = rest / 4;
      const int cout = ng * 16 + (lane & 15);
      const int cin = ((lane >> 4) << 3) + j;
      wf2[idx] = f2bf(w2[((size_t)cout * 32 + cin) * 9 + tap]);
    } else {            // conv3: CIN=64, COUT=128, KC=2, NG=8
      idx -= 18432;
      if (idx >= 73728) return;
      const int j = idx & 7;
      const int lane = (idx >> 3) & 63;
      int rest = idx >> 9;
      const int ng = rest % 8; rest /= 8;
      const int kc = rest & 1;
      const int tap = rest >> 1;
      const int cout = ng * 16 + (lane & 15);
      const int cin = kc * 32 + ((lane >> 4) << 3) + j;
      wf3[idx] = f2bf(w3[((size_t)cout * 64 + cin) * 9 + tap]);
    }
    return;
  }
  if (blockIdx.x >= 256) return;

  // ---- conv1: 3->32, fp32 VALU, raw y1 bf16 NHWC + atomic stats ----
  const int w = threadIdx.x, h = blockIdx.x, b = blockIdx.y;
  int off[9]; float msk[9];
  #pragma unroll
  for (int dh = -1; dh <= 1; ++dh)
    #pragma unroll
    for (int dw = -1; dw <= 1; ++dw) {
      int t9 = (dh + 1) * 3 + (dw + 1);
      int hh = h + dh, ww = w + dw;
      bool ok = (hh >= 0) && (hh < HH) && (ww >= 0) && (ww < WW);
      int hc = min(max(hh, 0), HH - 1), wc = min(max(ww, 0), WW - 1);
      off[t9] = hc * WW + wc;
      msk[t9] = ok ? 1.0f : 0.0f;
    }
  const float* inb = in + (size_t)b * 3 * HWSZ;
  float acc[32];
  #pragma unroll
  for (int c = 0; c < 32; ++c) acc[c] = bias[c];
  for (int ci = 0; ci < 3; ++ci) {
    const float* p = inb + (size_t)ci * HWSZ;
    float v[9];
    #pragma unroll
    for (int t = 0; t < 9; ++t) v[t] = p[off[t]] * msk[t];
    #pragma unroll
    for (int c = 0; c < 32; ++c) {
      const float* wr = wgt + ((size_t)c * 3 + ci) * 9;
      #pragma unroll
      for (int t = 0; t < 9; ++t) acc[c] = fmaf(wr[t], v[t], acc[c]);
    }
  }
  __shared__ float red[4][32][2];
  const int lane = threadIdx.x & 63, wv = threadIdx.x >> 6;
  #pragma unroll
  for (int c = 0; c < 32; ++c) {
    float s = acc[c], q = acc[c] * acc[c];
    #pragma unroll
    for (int o = 32; o > 0; o >>= 1) { s += __shfl_down(s, o); q += __shfl_down(q, o); }
    if (lane == 0) { red[wv][c][0] = s; red[wv][c][1] = q; }
  }
  uint4* o4 = (uint4*)(out + ((size_t)((b * 256 + h) * 256 + w)) * 32);
  #pragma unroll
  for (int i = 0; i < 4; ++i) {
    uint4 u;
    u.x = pack2bf(acc[8 * i + 0], acc[8 * i + 1]);
    u.y = pack2bf(acc[8 * i + 2], acc[8 * i + 3]);
    u.z = pack2bf(acc[8 * i + 4], acc[8 * i + 5]);
    u.w = pack2bf(acc[8 * i + 6], acc[8 * i + 7]);
    o4[i] = u;
  }
  __syncthreads();
  if (threadIdx.x < 64) {
    int c = threadIdx.x >> 1, j = threadIdx.x & 1;
    float r = red[0][c][j] + red[1][c][j] + red[2][c][j] + red[3][c][j];
    atomicAdd(&totals1[j * 32 + c], r);  // [sum32 | sumsq32]
  }
}

// ---- MFMA conv: 64px x 2 ROWS x COUT per block, PADDED affine LDS ---------
// Input-layer BN scale/shift computed INLINE per block from totals_in
// (atomic-accumulated by producer) + gamma/beta -> LDS; staging applies
// BN+lrelu on unpack. Own stats atomic-added to totals_out.
template<int CIN, int COUT, bool WRITE_OUT, int MINW>
__global__ __launch_bounds__(256, MINW) void conv_mfma(
    const unsigned short* __restrict__ in, const unsigned short* __restrict__ wf,
    const float* __restrict__ bias,
    const float* __restrict__ totals_in, const float* __restrict__ gamma_in,
    const float* __restrict__ beta_in,
    unsigned short* __restrict__ out, float* __restrict__ totals_out)
{
  constexpr int KC = CIN / 32;
  constexpr int NG = COUT / 16;
  constexpr int NF = COUT / 32;       // n-frags per wave (2 n-waves)
  constexpr int CH8 = CIN / 8;        // 16B chunks per pixel
  constexpr int CH8_LOG = (CH8 == 4) ? 2 : 3;
  constexpr int CPAD = CIN + 8;       // padded pixel stride (halfwords)
  constexpr int CHUNKS = 4 * 66 * CH8;

  const int tid = threadIdx.x, lane = tid & 63, wv = tid >> 6;
  const int wave_m = wv >> 1, wave_n = wv & 1;
  const int h0 = blockIdx.y * 2, b = blockIdx.z, w0 = blockIdx.x * 64;
  const size_t inb = (size_t)b * HWSZ * CIN;

  __shared__ __align__(16) unsigned short lds[4 * 66 * CPAD];
  __shared__ __align__(16) float scsh[2][CIN];

  // inline BN fold for the INPUT layer (replaces reduce_stats kernel)
  if (tid < CIN) {
    float s = totals_in[tid], q = totals_in[CIN + tid];
    float mean = s / BN_N;
    float var = q / BN_N - mean * mean;
    float rstd = rsqrtf(var + 1e-5f);
    float sc = gamma_in[tid] * rstd;
    scsh[0][tid] = sc;
    scsh[1][tid] = beta_in[tid] - mean * sc;
  }
  __syncthreads();

  // stage 4 rows x 66 px, BN(scale/shift)+leakyReLU applied on unpack
  for (int c = tid; c < CHUNKS; c += 256) {
    const int r = c / (66 * CH8);
    const int rem = c - r * (66 * CH8);
    const int px = rem >> CH8_LOG, ck = rem & (CH8 - 1);
    const int hi = h0 + r - 1, wi = w0 - 1 + px;
    uint4 v = make_uint4(0u, 0u, 0u, 0u);
    if ((unsigned)hi < 256u && (unsigned)wi < 256u) {
      uint4 raw = *(const uint4*)&in[inb + ((size_t)hi * 256 + wi) * CIN + ck * 8];
      const float4 s0 = *(const float4*)&scsh[0][ck * 8];
      const float4 s1 = *(const float4*)&scsh[0][ck * 8 + 4];
      const float4 t0 = *(const float4*)&scsh[1][ck * 8];
      const float4 t1 = *(const float4*)&scsh[1][ck * 8 + 4];
      const float scs[8] = {s0.x, s0.y, s0.z, s0.w, s1.x, s1.y, s1.z, s1.w};
      const float shs[8] = {t0.x, t0.y, t0.z, t0.w, t1.x, t1.y, t1.z, t1.w};
      unsigned int* u = (unsigned int*)&raw;
      unsigned int* o = (unsigned int*)&v;
      #pragma unroll
      for (int p = 0; p < 4; ++p) {
        float a = bf2f((unsigned short)(u[p] & 0xffff));
        float d = bf2f((unsigned short)(u[p] >> 16));
        float ya = a * scs[2 * p] + shs[2 * p];
        float yd = d * scs[2 * p + 1] + shs[2 * p + 1];
        ya = fmaxf(ya, 0.01f * ya);
        yd = fmaxf(yd, 0.01f * yd);
        o[p] = pack2bf(ya, yd);
      }
    }
    *(uint4*)&lds[(r * 66 + px) * CPAD + ck * 8] = v;
  }
  __syncthreads();

  const int j15 = lane & 15, q4 = lane >> 4;
  const int base_px = wave_m * 32 + j15;
  const unsigned short* abase = &lds[base_px * CPAD + q4 * 8];

  floatx4 acc[2][2][NF];  // [row][mf][nf]
  #pragma unroll
  for (int rr = 0; rr < 2; ++rr)
    #pragma unroll
    for (int mf = 0; mf < 2; ++mf)
      #pragma unroll
      for (int nf = 0; nf < NF; ++nf) acc[rr][mf][nf] = (floatx4){0.f, 0.f, 0.f, 0.f};

  #pragma unroll
  for (int dh = 0; dh < 3; ++dh) {
    #pragma unroll
    for (int dw = 0; dw < 3; ++dw) {
      #pragma unroll
      for (int kc = 0; kc < KC; ++kc) {
        const int tap = dh * 3 + dw;
        short8 bg[NF];
        #pragma unroll
        for (int nf = 0; nf < NF; ++nf)
          bg[nf] = *(const short8*)&wf[((((tap * KC + kc) * NG) + wave_n * NF + nf) * 64 + lane) * 8];
        #pragma unroll
        for (int rr = 0; rr < 2; ++rr) {
          short8 a[2];
          #pragma unroll
          for (int mf = 0; mf < 2; ++mf)
            a[mf] = *(const short8*)&abase[((rr + dh) * 66 + dw + mf * 16) * CPAD + kc * 32];
          #pragma unroll
          for (int mf = 0; mf < 2; ++mf)
            #pragma unroll
            for (int nf = 0; nf < NF; ++nf)
              acc[rr][mf][nf] = __builtin_amdgcn_mfma_f32_16x16x32_bf16(a[mf], bg[nf], acc[rr][mf][nf], 0, 0, 0);
        }
      }
    }
  }

  // epilogue: +bias, per-wave stats over both rows, optional bf16 NHWC store
  float bv[NF], sa[NF], qa[NF];
  #pragma unroll
  for (int nf = 0; nf < NF; ++nf) {
    bv[nf] = bias[wave_n * (COUT / 2) + nf * 16 + j15];
    sa[nf] = 0.f; qa[nf] = 0.f;
  }
  #pragma unroll
  for (int rr = 0; rr < 2; ++rr) {
    const size_t orow = ((size_t)(b * 256 + (h0 + rr)) * 256 + w0);
    #pragma unroll
    for (int nf = 0; nf < NF; ++nf) {
      const int ch = wave_n * (COUT / 2) + nf * 16 + j15;
      #pragma unroll
      for (int mf = 0; mf < 2; ++mf)
        #pragma unroll
        for (int r4 = 0; r4 < 4; ++r4) {
          float y = acc[rr][mf][nf][r4] + bv[nf];
          sa[nf] += y; qa[nf] += y * y;
          if constexpr (WRITE_OUT) {
            const int p = wave_m * 32 + mf * 16 + q4 * 4 + r4;
            out[(orow + p) * COUT + ch] = f2bf(y);
          }
        }
    }
  }

  __syncthreads();
  float* red = (float*)lds;  // [4][NF][16] sums, then [4][NF][16] sumsq
  #pragma unroll
  for (int nf = 0; nf < NF; ++nf) {
    float s = sa[nf], q = qa[nf];
    s += __shfl_xor(s, 16); s += __shfl_xor(s, 32);
    q += __shfl_xor(q, 16); q += __shfl_xor(q, 32);
    if (lane < 16) {
      red[(wv * NF + nf) * 16 + lane] = s;
      red[4 * NF * 16 + (wv * NF + nf) * 16 + lane] = q;
    }
  }
  __syncthreads();
  if (tid < COUT) {
    const int wn = tid / (COUT / 2), rr = tid % (COUT / 2);
    const int nf = rr >> 4, li = rr & 15;
    float s = red[(wn * NF + nf) * 16 + li] + red[((wn + 2) * NF + nf) * 16 + li];
    float q = red[4 * NF * 16 + (wn * NF + nf) * 16 + li] +
              red[4 * NF * 16 + ((wn + 2) * NF + nf) * 16 + li];
    atomicAdd(&totals_out[tid], s);          // [sumCOUT | sumsqCOUT]
    atomicAdd(&totals_out[COUT + tid], q);
  }
}

// ---- fused outputs: patches (blocks 0..13) + encode (blocks 14..17) -------
// encode: conv3 at 8 pixels (n_xy) on RAW y2 (bn2+lrelu on read),
// bn3 computed inline from totals3, applied at end.
__global__ __launch_bounds__(256) void outputs_kernel(
    const float* __restrict__ img, const int* __restrict__ axy,
    const int* __restrict__ pxy, const int* __restrict__ nxy,
    const unsigned short* __restrict__ y2, const float* __restrict__ wgt,
    const float* __restrict__ bias,
    const float* __restrict__ totals2, const float* __restrict__ g2,
    const float* __restrict__ b2v,
    const float* __restrict__ totals3, const float* __restrict__ g3,
    const float* __restrict__ b3v,
    float* __restrict__ out)
{
  if (blockIdx.x < 14) {
    const int i = blockIdx.x * 256 + threadIdx.x;
    if (i >= 3 * BATCH * 3 * 49) return;
    const int arr = i / 1176, r = i % 1176;
    const int b = r / 147, q = r % 147;
    const int c = q / 49, s = q % 49;
    const int ph = s / 7, pw = s % 7;
    const int* xy = (arr == 0) ? axy : ((arr == 1) ? pxy : nxy);
    const int x = xy[(b * 32 + 31) * 2 + 0];
    const int y = xy[(b * 32 + 31) * 2 + 1];
    out[i] = img[((size_t)(b * 3 + c) * HH + (x - 3 + ph)) * WW + (y - 3 + pw)];
  } else {
    const int b = (blockIdx.x - 14) * 2 + (threadIdx.x >> 7);
    const int co = threadIdx.x & 127;
    const int x = nxy[(b * 32 + 31) * 2 + 0];
    const int y = nxy[(b * 32 + 31) * 2 + 1];
    // bn2 scale/shift for input reads: computed per-thread into LDS
    __shared__ float sc2[2][64];
    if (threadIdx.x < 64) {
      float s = totals2[threadIdx.x], q = totals2[64 + threadIdx.x];
      float mean = s / BN_N;
      float var = q / BN_N - mean * mean;
      float rstd = rsqrtf(var + 1e-5f);
      float sc = g2[threadIdx.x] * rstd;
      sc2[0][threadIdx.x] = sc;
      sc2[1][threadIdx.x] = b2v[threadIdx.x] - mean * sc;
    }
    __syncthreads();
    float acc = bias[co];
    for (int ci = 0; ci < 64; ++ci) {
      const float s2 = sc2[0][ci], h2 = sc2[1][ci];
      #pragma unroll
      for (int dh = -1; dh <= 1; ++dh)
        #pragma unroll
        for (int dw = -1; dw <= 1; ++dw) {
          float v = bf2f(y2[((size_t)(b * 256 + x + dh) * 256 + (y + dw)) * 64 + ci]);
          v = v * s2 + h2;
          v = fmaxf(v, 0.01f * v);
          acc = fmaf(wgt[((size_t)co * 64 + ci) * 9 + (dh + 1) * 3 + (dw + 1)], v, acc);
        }
    }
    // bn3 inline
    float s = totals3[co], q = totals3[128 + co];
    float mean = s / BN_N;
    float var = q / BN_N - mean * mean;
    float rstd = rsqrtf(var + 1e-5f);
    float sc3 = g3[co] * rstd;
    float sh3 = b3v[co] - mean * sc3;
    const float yv = acc * sc3 + sh3;
    out[3528 + b * 128 + co] = fmaxf(yv, 0.01f * yv);
  }
}

extern "C" void kernel_launch(void* const* d_in, const int* in_sizes, int n_in,
                              void* d_out, int out_size, void* d_ws, size_t ws_size,
                              hipStream_t stream)
{
  const float* image = (const float*)d_in[0];
  const int* axy = (const int*)d_in[1];
  const int* pxy = (const int*)d_in[2];
  const int* nxy = (const int*)d_in[3];
  const float* c1w = (const float*)d_in[4];
  const float* c1b = (const float*)d_in[5];
  const float* g1 = (const float*)d_in[6];
  const float* b1 = (const float*)d_in[7];
  const float* c2w = (const float*)d_in[8];
  const float* c2b = (const float*)d_in[9];
  const float* g2 = (const float*)d_in[10];
  const float* b2 = (const float*)d_in[11];
  const float* c3w = (const float*)d_in[12];
  const float* c3b = (const float*)d_in[13];
  const float* g3 = (const float*)d_in[14];
  const float* b3 = (const float*)d_in[15];
  float* out = (float*)d_out;

  // workspace layout (~101 MB)
  unsigned short* zb1 = (unsigned short*)d_ws;            // raw y1, 16.78M bf16
  unsigned short* zb2 = zb1 + (size_t)8 * 32 * HWSZ;      // raw y2, 33.55M bf16
  unsigned short* wf2 = zb2 + (size_t)8 * 64 * HWSZ;      // 18432
  unsigned short* wf3 = wf2 + 18432;                      // 73728
  float* totals1 = (float*)(wf3 + 73728);                 // 64
  float* totals2 = totals1 + 64;                          // 128
  float* totals3 = totals2 + 128;                         // 256

  // zero the atomic accumulators (448 floats)
  hipMemsetAsync(totals1, 0, 448 * sizeof(float), stream);

  // conv1 (y<8) + weight prep (y==8)
  conv1_prep<<<dim3(360, 9), 256, 0, stream>>>(
      image, c1w, c1b, zb1, totals1, c2w, c3w, wf2, wf3);

  // layer 2: 32 -> 64 (MFMA; bn1 inline from totals1; raw y2 out + stats)
  conv_mfma<32, 64, true, 2><<<dim3(4, 128, 8), 256, 0, stream>>>(
      zb1, wf2, c2b, totals1, g1, b1, zb2, totals2);

  // layer 3: 64 -> 128 (MFMA; bn2 inline from totals2; stats only)
  conv_mfma<64, 128, false, 2><<<dim3(4, 128, 8), 256, 0, stream>>>(
      zb2, wf3, c3b, totals2, g2, b2, nullptr, totals3);

  // outputs: patches + encode (bn2 on reads, bn3 inline from totals3)
  outputs_kernel<<<18, 256, 0, stream>>>(image, axy, pxy, nxy, zb2, c3w, c3b,
                                         totals2, g2, b2, totals3, g3, b3, out);
}

// Round 12
// 299.031 us; speedup vs baseline: 1.4568x; 1.4568x over previous
//
#include <hip/hip_runtime.h>
#include <math.h>

#define HH 256
#define WW 256
#define BATCH 8
#define HWSZ 65536
#define NPB2 4096  // partial slots for conv2/conv3 (4096 blocks)

typedef __attribute__((ext_vector_type(8))) short short8;
typedef __attribute__((ext_vector_type(4))) float floatx4;

// round-half-up bf16 pack: 2 VALU ops, max err 0.5 ulp
__device__ __forceinline__ unsigned short f2bf(float f) {
  union { float f; unsigned int u; } v; v.f = f;
  return (unsigned short)((v.u + 0x8000u) >> 16);
}
// pack two fp32 -> bf16x2 (lo=a, hi=d): 5 VALU ops
__device__ __forceinline__ unsigned int pack2bf(float a, float d) {
  union { float f; unsigned int u; } va, vd; va.f = a; vd.f = d;
  return ((va.u + 0x8000u) >> 16) | ((vd.u + 0x8000u) & 0xffff0000u);
}
__device__ __forceinline__ float bf2f(unsigned short u) {
  union { unsigned int u; float f; } v; v.u = ((unsigned int)u) << 16;
  return v.f;
}

// ---- conv1 (grid y<8, x<256) + weight pre-swizzle (y==8) ------------------
__global__ __launch_bounds__(256) void conv1_prep(
    const float* __restrict__ in, const float* __restrict__ wgt,
    const float* __restrict__ bias, unsigned short* __restrict__ out,
    float* __restrict__ partial,
    const float* __restrict__ w2, const float* __restrict__ w3,
    unsigned short* __restrict__ wf2, unsigned short* __restrict__ wf3)
{
  if (blockIdx.y == 8) {  // prep path: 360 x-blocks cover 92160 elems
    int idx = blockIdx.x * 256 + threadIdx.x;
    if (idx < 18432) {  // conv2: CIN=32, COUT=64, KC=1, NG=4
      const int j = idx & 7;
      const int lane = (idx >> 3) & 63;
      int rest = idx >> 9;
      const int ng = rest % 4;
      const int tap = rest / 4;
      const int cout = ng * 16 + (lane & 15);
      const int cin = ((lane >> 4) << 3) + j;
      wf2[idx] = f2bf(w2[((size_t)cout * 32 + cin) * 9 + tap]);
    } else {            // conv3: CIN=64, COUT=128, KC=2, NG=8
      idx -= 18432;
      if (idx >= 73728) return;
      const int j = idx & 7;
      const int lane = (idx >> 3) & 63;
      int rest = idx >> 9;
      const int ng = rest % 8; rest /= 8;
      const int kc = rest & 1;
      const int tap = rest >> 1;
      const int cout = ng * 16 + (lane & 15);
      const int cin = kc * 32 + ((lane >> 4) << 3) + j;
      wf3[idx] = f2bf(w3[((size_t)cout * 64 + cin) * 9 + tap]);
    }
    return;
  }
  if (blockIdx.x >= 256) return;

  // conv1: 3->32, fp32 VALU, raw y1 (bias, NO bn) bf16 NHWC direct store
  const int w = threadIdx.x, h = blockIdx.x, b = blockIdx.y;
  int off[9]; float msk[9];
  #pragma unroll
  for (int dh = -1; dh <= 1; ++dh)
    #pragma unroll
    for (int dw = -1; dw <= 1; ++dw) {
      int t9 = (dh + 1) * 3 + (dw + 1);
      int hh = h + dh, ww = w + dw;
      bool ok = (hh >= 0) && (hh < HH) && (ww >= 0) && (ww < WW);
      int hc = min(max(hh, 0), HH - 1), wc = min(max(ww, 0), WW - 1);
      off[t9] = hc * WW + wc;
      msk[t9] = ok ? 1.0f : 0.0f;
    }
  const float* inb = in + (size_t)b * 3 * HWSZ;
  float acc[32];
  #pragma unroll
  for (int c = 0; c < 32; ++c) acc[c] = bias[c];
  for (int ci = 0; ci < 3; ++ci) {
    const float* p = inb + (size_t)ci * HWSZ;
    float v[9];
    #pragma unroll
    for (int t = 0; t < 9; ++t) v[t] = p[off[t]] * msk[t];
    #pragma unroll
    for (int c = 0; c < 32; ++c) {
      const float* wr = wgt + ((size_t)c * 3 + ci) * 9;
      #pragma unroll
      for (int t = 0; t < 9; ++t) acc[c] = fmaf(wr[t], v[t], acc[c]);
    }
  }
  __shared__ float red[4][32][2];
  const int lane = threadIdx.x & 63, wv = threadIdx.x >> 6;
  #pragma unroll
  for (int c = 0; c < 32; ++c) {
    float s = acc[c], q = acc[c] * acc[c];
    #pragma unroll
    for (int o = 32; o > 0; o >>= 1) { s += __shfl_down(s, o); q += __shfl_down(q, o); }
    if (lane == 0) { red[wv][c][0] = s; red[wv][c][1] = q; }
  }
  uint4* o4 = (uint4*)(out + ((size_t)((b * 256 + h) * 256 + w)) * 32);
  #pragma unroll
  for (int i = 0; i < 4; ++i) {
    uint4 u;
    u.x = pack2bf(acc[8 * i + 0], acc[8 * i + 1]);
    u.y = pack2bf(acc[8 * i + 2], acc[8 * i + 3]);
    u.z = pack2bf(acc[8 * i + 4], acc[8 * i + 5]);
    u.w = pack2bf(acc[8 * i + 6], acc[8 * i + 7]);
    o4[i] = u;
  }
  __syncthreads();
  if (threadIdx.x < 64) {
    int c = threadIdx.x >> 1, j = threadIdx.x & 1;
    float r = red[0][c][j] + red[1][c][j] + red[2][c][j] + red[3][c][j];
    int pb = b * 256 + h;
    partial[((size_t)c * 2 + j) * 2048 + pb] = r;
  }
}

// ---- MFMA conv: 64px x 2 ROWS x COUT per block, PADDED affine LDS ---------
// 1D grid with XCD-aware decode: lin%8 = XCD (round-robin dispatch), each
// XCD owns a contiguous 32-row slab per batch so halo rows between adjacent
// h-tiles hit the same per-XCD L2 instead of re-fetching from HBM.
template<int CIN, int COUT, bool WRITE_OUT, int MINW>
__global__ __launch_bounds__(256, MINW) void conv_mfma(
    const unsigned short* __restrict__ in, const unsigned short* __restrict__ wf,
    const float* __restrict__ bias,
    const float* __restrict__ bn_sc, const float* __restrict__ bn_sh,
    unsigned short* __restrict__ out, float* __restrict__ partial)
{
  constexpr int KC = CIN / 32;
  constexpr int NG = COUT / 16;
  constexpr int NF = COUT / 32;       // n-frags per wave (2 n-waves)
  constexpr int CH8 = CIN / 8;        // 16B chunks per pixel
  constexpr int CH8_LOG = (CH8 == 4) ? 2 : 3;
  constexpr int CPAD = CIN + 8;       // padded pixel stride (halfwords)
  constexpr int CHUNKS = 4 * 66 * CH8;

  const int tid = threadIdx.x, lane = tid & 63, wv = tid >> 6;
  const int wave_m = wv >> 1, wave_n = wv & 1;

  // XCD-aware decode: lin = slot*8 + xcd; XCD 'xcd' covers h-tiles
  // [xcd*16, xcd*16+16) for each batch in turn (64 slots per batch-slab).
  const int lin = blockIdx.x;
  const int xcd = lin & 7, slot = lin >> 3;
  const int b = slot >> 6;            // 0..7
  const int rem = slot & 63;          // 0..63
  const int h0 = ((xcd << 4) + (rem >> 2)) * 2;
  const int w0 = (rem & 3) * 64;
  const size_t inb = (size_t)b * HWSZ * CIN;

  __shared__ __align__(16) unsigned short lds[4 * 66 * CPAD];

  // stage 4 rows x 66 px, BN(scale/shift)+leakyReLU applied on unpack
  for (int c = tid; c < CHUNKS; c += 256) {
    const int r = c / (66 * CH8);
    const int rem2 = c - r * (66 * CH8);
    const int px = rem2 >> CH8_LOG, ck = rem2 & (CH8 - 1);
    const int hi = h0 + r - 1, wi = w0 - 1 + px;
    uint4 v = make_uint4(0u, 0u, 0u, 0u);
    if ((unsigned)hi < 256u && (unsigned)wi < 256u) {
      uint4 raw = *(const uint4*)&in[inb + ((size_t)hi * 256 + wi) * CIN + ck * 8];
      const float4 s0 = *(const float4*)&bn_sc[ck * 8];
      const float4 s1 = *(const float4*)&bn_sc[ck * 8 + 4];
      const float4 t0 = *(const float4*)&bn_sh[ck * 8];
      const float4 t1 = *(const float4*)&bn_sh[ck * 8 + 4];
      const float scs[8] = {s0.x, s0.y, s0.z, s0.w, s1.x, s1.y, s1.z, s1.w};
      const float shs[8] = {t0.x, t0.y, t0.z, t0.w, t1.x, t1.y, t1.z, t1.w};
      unsigned int* u = (unsigned int*)&raw;
      unsigned int* o = (unsigned int*)&v;
      #pragma unroll
      for (int p = 0; p < 4; ++p) {
        float a = bf2f((unsigned short)(u[p] & 0xffff));
        float d = bf2f((unsigned short)(u[p] >> 16));
        float ya = a * scs[2 * p] + shs[2 * p];
        float yd = d * scs[2 * p + 1] + shs[2 * p + 1];
        ya = fmaxf(ya, 0.01f * ya);
        yd = fmaxf(yd, 0.01f * yd);
        o[p] = pack2bf(ya, yd);
      }
    }
    *(uint4*)&lds[(r * 66 + px) * CPAD + ck * 8] = v;
  }
  __syncthreads();

  const int j15 = lane & 15, q4 = lane >> 4;
  const int base_px = wave_m * 32 + j15;
  const unsigned short* abase = &lds[base_px * CPAD + q4 * 8];

  floatx4 acc[2][2][NF];  // [row][mf][nf]
  #pragma unroll
  for (int rr = 0; rr < 2; ++rr)
    #pragma unroll
    for (int mf = 0; mf < 2; ++mf)
      #pragma unroll
      for (int nf = 0; nf < NF; ++nf) acc[rr][mf][nf] = (floatx4){0.f, 0.f, 0.f, 0.f};

  #pragma unroll
  for (int dh = 0; dh < 3; ++dh) {
    #pragma unroll
    for (int dw = 0; dw < 3; ++dw) {
      #pragma unroll
      for (int kc = 0; kc < KC; ++kc) {
        const int tap = dh * 3 + dw;
        short8 bg[NF];
        #pragma unroll
        for (int nf = 0; nf < NF; ++nf)
          bg[nf] = *(const short8*)&wf[((((tap * KC + kc) * NG) + wave_n * NF + nf) * 64 + lane) * 8];
        #pragma unroll
        for (int rr = 0; rr < 2; ++rr) {
          short8 a[2];
          #pragma unroll
          for (int mf = 0; mf < 2; ++mf)
            a[mf] = *(const short8*)&abase[((rr + dh) * 66 + dw + mf * 16) * CPAD + kc * 32];
          #pragma unroll
          for (int mf = 0; mf < 2; ++mf)
            #pragma unroll
            for (int nf = 0; nf < NF; ++nf)
              acc[rr][mf][nf] = __builtin_amdgcn_mfma_f32_16x16x32_bf16(a[mf], bg[nf], acc[rr][mf][nf], 0, 0, 0);
        }
      }
    }
  }

  // epilogue: +bias, per-wave stats over both rows, optional bf16 NHWC store
  float bv[NF], sa[NF], qa[NF];
  #pragma unroll
  for (int nf = 0; nf < NF; ++nf) {
    bv[nf] = bias[wave_n * (COUT / 2) + nf * 16 + j15];
    sa[nf] = 0.f; qa[nf] = 0.f;
  }
  #pragma unroll
  for (int rr = 0; rr < 2; ++rr) {
    const size_t orow = ((size_t)(b * 256 + (h0 + rr)) * 256 + w0);
    #pragma unroll
    for (int nf = 0; nf < NF; ++nf) {
      const int ch = wave_n * (COUT / 2) + nf * 16 + j15;
      #pragma unroll
      for (int mf = 0; mf < 2; ++mf)
        #pragma unroll
        for (int r4 = 0; r4 < 4; ++r4) {
          float y = acc[rr][mf][nf][r4] + bv[nf];
          sa[nf] += y; qa[nf] += y * y;
          if constexpr (WRITE_OUT) {
            const int p = wave_m * 32 + mf * 16 + q4 * 4 + r4;
            out[(orow + p) * COUT + ch] = f2bf(y);
          }
        }
    }
  }

  __syncthreads();
  float* red = (float*)lds;  // [4][NF][16] sums, then [4][NF][16] sumsq
  #pragma unroll
  for (int nf = 0; nf < NF; ++nf) {
    float s = sa[nf], q = qa[nf];
    s += __shfl_xor(s, 16); s += __shfl_xor(s, 32);
    q += __shfl_xor(q, 16); q += __shfl_xor(q, 32);
    if (lane < 16) {
      red[(wv * NF + nf) * 16 + lane] = s;
      red[4 * NF * 16 + (wv * NF + nf) * 16 + lane] = q;
    }
  }
  __syncthreads();
  if (tid < COUT) {
    const int wn = tid / (COUT / 2), rr = tid % (COUT / 2);
    const int nf = rr >> 4, li = rr & 15;
    float s = red[(wn * NF + nf) * 16 + li] + red[((wn + 2) * NF + nf) * 16 + li];
    float q = red[4 * NF * 16 + (wn * NF + nf) * 16 + li] +
              red[4 * NF * 16 + ((wn + 2) * NF + nf) * 16 + li];
    partial[((size_t)tid * 2 + 0) * NPB2 + lin] = s;
    partial[((size_t)tid * 2 + 1) * NPB2 + lin] = q;
  }
}

// ---- fold partials into scale/shift ---------------------------------------
__global__ __launch_bounds__(256) void reduce_stats(
    const float* __restrict__ partial, const float* __restrict__ gamma,
    const float* __restrict__ beta, float* __restrict__ scale,
    float* __restrict__ shift, int npb)
{
  const int c = blockIdx.x;
  float s = 0.f, q = 0.f;
  for (int i = threadIdx.x; i < npb; i += 256) {
    s += partial[((size_t)c * 2 + 0) * npb + i];
    q += partial[((size_t)c * 2 + 1) * npb + i];
  }
  #pragma unroll
  for (int o = 32; o > 0; o >>= 1) { s += __shfl_down(s, o); q += __shfl_down(q, o); }
  __shared__ float rs[4][2];
  const int lane = threadIdx.x & 63, wv = threadIdx.x >> 6;
  if (lane == 0) { rs[wv][0] = s; rs[wv][1] = q; }
  __syncthreads();
  if (threadIdx.x == 0) {
    s = rs[0][0] + rs[1][0] + rs[2][0] + rs[3][0];
    q = rs[0][1] + rs[1][1] + rs[2][1] + rs[3][1];
    const float N = (float)((size_t)BATCH * HWSZ);
    float mean = s / N;
    float var = q / N - mean * mean;
    float rstd = 1.0f / sqrtf(var + 1e-5f);
    float sc = gamma[c] * rstd;
    scale[c] = sc;
    shift[c] = beta[c] - mean * sc;
  }
}

// ---- fused outputs: patches (blocks 0..13) + encode (blocks 14..17) -------
// encode: conv3 at 8 pixels (n_xy) on RAW y2 (bn2+lrelu on read), bn3 at end.
__global__ __launch_bounds__(256) void outputs_kernel(
    const float* __restrict__ img, const int* __restrict__ axy,
    const int* __restrict__ pxy, const int* __restrict__ nxy,
    const unsigned short* __restrict__ y2, const float* __restrict__ wgt,
    const float* __restrict__ bias,
    const float* __restrict__ sc2, const float* __restrict__ sh2,
    const float* __restrict__ scale, const float* __restrict__ shift,
    float* __restrict__ out)
{
  if (blockIdx.x < 14) {
    const int i = blockIdx.x * 256 + threadIdx.x;
    if (i >= 3 * BATCH * 3 * 49) return;
    const int arr = i / 1176, r = i % 1176;
    const int b = r / 147, q = r % 147;
    const int c = q / 49, s = q % 49;
    const int ph = s / 7, pw = s % 7;
    const int* xy = (arr == 0) ? axy : ((arr == 1) ? pxy : nxy);
    const int x = xy[(b * 32 + 31) * 2 + 0];
    const int y = xy[(b * 32 + 31) * 2 + 1];
    out[i] = img[((size_t)(b * 3 + c) * HH + (x - 3 + ph)) * WW + (y - 3 + pw)];
  } else {
    const int b = (blockIdx.x - 14) * 2 + (threadIdx.x >> 7);
    const int co = threadIdx.x & 127;
    const int x = nxy[(b * 32 + 31) * 2 + 0];
    const int y = nxy[(b * 32 + 31) * 2 + 1];
    float acc = bias[co];
    for (int ci = 0; ci < 64; ++ci) {
      const float s2 = sc2[ci], h2 = sh2[ci];
      #pragma unroll
      for (int dh = -1; dh <= 1; ++dh)
        #pragma unroll
        for (int dw = -1; dw <= 1; ++dw) {
          float v = bf2f(y2[((size_t)(b * 256 + x + dh) * 256 + (y + dw)) * 64 + ci]);
          v = v * s2 + h2;
          v = fmaxf(v, 0.01f * v);
          acc = fmaf(wgt[((size_t)co * 64 + ci) * 9 + (dh + 1) * 3 + (dw + 1)], v, acc);
        }
    }
    const float yv = acc * scale[co] + shift[co];
    out[3528 + b * 128 + co] = fmaxf(yv, 0.01f * yv);
  }
}

extern "C" void kernel_launch(void* const* d_in, const int* in_sizes, int n_in,
                              void* d_out, int out_size, void* d_ws, size_t ws_size,
                              hipStream_t stream)
{
  const float* image = (const float*)d_in[0];
  const int* axy = (const int*)d_in[1];
  const int* pxy = (const int*)d_in[2];
  const int* nxy = (const int*)d_in[3];
  const float* c1w = (const float*)d_in[4];
  const float* c1b = (const float*)d_in[5];
  const float* g1 = (const float*)d_in[6];
  const float* b1 = (const float*)d_in[7];
  const float* c2w = (const float*)d_in[8];
  const float* c2b = (const float*)d_in[9];
  const float* g2 = (const float*)d_in[10];
  const float* b2 = (const float*)d_in[11];
  const float* c3w = (const float*)d_in[12];
  const float* c3b = (const float*)d_in[13];
  const float* g3 = (const float*)d_in[14];
  const float* b3 = (const float*)d_in[15];
  float* out = (float*)d_out;

  // workspace layout (~105 MB)
  unsigned short* zb1 = (unsigned short*)d_ws;            // raw y1, 16.78M bf16
  unsigned short* zb2 = zb1 + (size_t)8 * 32 * HWSZ;      // raw y2, 33.55M bf16
  unsigned short* wf2 = zb2 + (size_t)8 * 64 * HWSZ;      // 18432
  unsigned short* wf3 = wf2 + 18432;                      // 73728
  float* partial = (float*)(wf3 + 73728);                 // 128*2*4096 floats
  float* scale1 = partial + (size_t)128 * 2 * NPB2;
  float* shift1 = scale1 + 32;
  float* scale2 = shift1 + 32;
  float* shift2 = scale2 + 64;
  float* scale3 = shift2 + 64;
  float* shift3 = scale3 + 128;

  // conv1 (y<8) + weight prep (y==8)
  conv1_prep<<<dim3(360, 9), 256, 0, stream>>>(
      image, c1w, c1b, zb1, partial, c2w, c3w, wf2, wf3);
  reduce_stats<<<32, 256, 0, stream>>>(partial, g1, b1, scale1, shift1, 2048);

  // layer 2: 32 -> 64 (MFMA; bn1+lrelu fused in staging; raw y2 out + stats)
  conv_mfma<32, 64, true, 2><<<4096, 256, 0, stream>>>(
      zb1, wf2, c2b, scale1, shift1, zb2, partial);
  reduce_stats<<<64, 256, 0, stream>>>(partial, g2, b2, scale2, shift2, NPB2);

  // layer 3: 64 -> 128 (MFMA; bn2+lrelu fused in staging; stats only)
  conv_mfma<64, 128, false, 2><<<4096, 256, 0, stream>>>(
      zb2, wf3, c3b, scale2, shift2, nullptr, partial);
  reduce_stats<<<128, 256, 0, stream>>>(partial, g3, b3, scale3, shift3, NPB2);

  // outputs: patches + encode fused (bn2 on reads, bn3 at end)
  outputs_kernel<<<18, 256, 0, stream>>>(image, axy, pxy, nxy, zb2, c3w, c3b,
                                         scale2, shift2, scale3, shift3, out);
}

// Round 13
// 268.902 us; speedup vs baseline: 1.6200x; 1.1120x over previous
//
#include <hip/hip_runtime.h>
#include <math.h>

#define HH 256
#define WW 256
#define BATCH 8
#define HWSZ 65536
#define NPB2 4096  // partial slots (4096 blocks for all three convs)

typedef __attribute__((ext_vector_type(8))) short short8;
typedef __attribute__((ext_vector_type(4))) float floatx4;

// round-half-up bf16 pack: 2 VALU ops, max err 0.5 ulp
__device__ __forceinline__ unsigned short f2bf(float f) {
  union { float f; unsigned int u; } v; v.f = f;
  return (unsigned short)((v.u + 0x8000u) >> 16);
}
// pack two fp32 -> bf16x2 (lo=a, hi=d): 5 VALU ops
__device__ __forceinline__ unsigned int pack2bf(float a, float d) {
  union { float f; unsigned int u; } va, vd; va.f = a; vd.f = d;
  return ((va.u + 0x8000u) >> 16) | ((vd.u + 0x8000u) & 0xffff0000u);
}
__device__ __forceinline__ float bf2f(unsigned short u) {
  union { unsigned int u; float f; } v; v.u = ((unsigned int)u) << 16;
  return v.f;
}

// ---- conv1 as im2col MFMA (blocks 0..4095) + wf2/wf3 prep (4096..4455) ----
// Tile: 64px x 2 rows x 32 cout. K = 32 (3ch x 9tap, padded with the LDS
// pad channel ci==3 which stays zero -> k>=27 contributes 0 automatically).
// A-lane mapping (m=lane&15, k=(lane>>4)*8+j) and C-layout epilogue are the
// same verified mappings used by conv_mfma for conv2/conv3.
__global__ __launch_bounds__(256) void conv1_mfma(
    const float* __restrict__ img, const float* __restrict__ w1,
    const float* __restrict__ bias, unsigned short* __restrict__ out,
    float* __restrict__ partial,
    const float* __restrict__ w2, const float* __restrict__ w3,
    unsigned short* __restrict__ wf2, unsigned short* __restrict__ wf3)
{
  const int lin = blockIdx.x;
  if (lin >= 4096) {  // ---- prep path: 360 blocks cover 92160 elems ----
    int idx = (lin - 4096) * 256 + threadIdx.x;
    if (idx < 18432) {  // conv2: CIN=32, COUT=64, KC=1, NG=4
      const int j = idx & 7;
      const int lane = (idx >> 3) & 63;
      int rest = idx >> 9;
      const int ng = rest % 4;
      const int tap = rest / 4;
      const int cout = ng * 16 + (lane & 15);
      const int cin = ((lane >> 4) << 3) + j;
      wf2[idx] = f2bf(w2[((size_t)cout * 32 + cin) * 9 + tap]);
    } else {            // conv3: CIN=64, COUT=128, KC=2, NG=8
      idx -= 18432;
      if (idx >= 73728) return;
      const int j = idx & 7;
      const int lane = (idx >> 3) & 63;
      int rest = idx >> 9;
      const int ng = rest % 8; rest /= 8;
      const int kc = rest & 1;
      const int tap = rest >> 1;
      const int cout = ng * 16 + (lane & 15);
      const int cin = kc * 32 + ((lane >> 4) << 3) + j;
      wf3[idx] = f2bf(w3[((size_t)cout * 64 + cin) * 9 + tap]);
    }
    return;
  }

  const int tid = threadIdx.x, lane = tid & 63, wv = tid >> 6;
  const int wave_m = wv >> 1, wave_n = wv & 1;
  const int xcd = lin & 7, slot = lin >> 3;
  const int b = slot >> 6;
  const int rem = slot & 63;
  const int h0 = ((xcd << 4) + (rem >> 2)) * 2;
  const int w0 = (rem & 3) * 64;

  __shared__ __align__(16) unsigned short simg[4 * 66 * 4];  // [row][px][3ch+pad]
  __shared__ __align__(16) unsigned short swf[2 * 64 * 8];   // conv1 B-frags
  __shared__ float red2[2][4][16];                           // [s|q][wv][li]

  // zero the image region (borders + pad channel stay 0)
  for (int t = tid; t < (4 * 66 * 4) / 2; t += 256)
    ((unsigned int*)simg)[t] = 0u;
  // build conv1 B-frags in LDS: swf[(nt*64+l)*8+j] = W1[nt*16+(l&15)][k], k=(l>>4)*8+j
  {
    const int t0 = tid * 4;
    #pragma unroll
    for (int u = 0; u < 4; ++u) {
      const int idx = t0 + u;
      const int j = idx & 7, l8 = (idx >> 3) & 63, nt = idx >> 9;
      const int k = ((l8 >> 4) << 3) + j;
      const int cout = nt * 16 + (l8 & 15);
      swf[idx] = (k < 27) ? f2bf(w1[cout * 27 + k]) : (unsigned short)0;
    }
  }
  __syncthreads();
  // stage image 3ch x 4 rows x 66 px as bf16 (px-contiguous per channel)
  for (int t = tid; t < 792; t += 256) {
    const int ci = t / 264, r2 = t - ci * 264;
    const int r = r2 / 66, px = r2 - r * 66;
    const int hi = h0 + r - 1, wi = w0 + px - 1;
    if ((unsigned)hi < 256u && (unsigned)wi < 256u)
      simg[(r * 66 + px) * 4 + ci] =
          f2bf(img[((size_t)(b * 3 + ci) * 256 + hi) * 256 + wi]);
  }
  __syncthreads();

  const int j15 = lane & 15, q4 = lane >> 4;
  // k-decode: off[j] for this lane's 8 k's (k>=27 -> ci==3 zero slot)
  int off[8];
  #pragma unroll
  for (int j = 0; j < 8; ++j) {
    const int k = q4 * 8 + j;
    const int ci = k / 9, tap = k - ci * 9;
    const int dh = tap / 3, dw = tap - dh * 3;
    off[j] = (dh * 66 + dw) * 4 + ci;
  }
  const int base_px = wave_m * 32 + j15;
  const short8 bg = *(const short8*)&swf[(wave_n * 64 + lane) * 8];

  floatx4 acc[2][2];
  #pragma unroll
  for (int rr = 0; rr < 2; ++rr)
    #pragma unroll
    for (int mf = 0; mf < 2; ++mf) {
      acc[rr][mf] = (floatx4){0.f, 0.f, 0.f, 0.f};
      union { short8 v; unsigned short e[8]; } a;
      const int ab = (rr * 66 + base_px + mf * 16) * 4;
      #pragma unroll
      for (int j = 0; j < 8; ++j) a.e[j] = simg[ab + off[j]];
      acc[rr][mf] = __builtin_amdgcn_mfma_f32_16x16x32_bf16(a.v, bg, acc[rr][mf], 0, 0, 0);
    }

  // epilogue: +bias, stats, bf16 NHWC store (C-layout as in conv_mfma)
  float sa = 0.f, qa = 0.f;
  const float bv = bias[wave_n * 16 + j15];
  #pragma unroll
  for (int rr = 0; rr < 2; ++rr) {
    const size_t orow = ((size_t)(b * 256 + (h0 + rr)) * 256 + w0);
    #pragma unroll
    for (int mf = 0; mf < 2; ++mf)
      #pragma unroll
      for (int r4 = 0; r4 < 4; ++r4) {
        float y = acc[rr][mf][r4] + bv;
        sa += y; qa += y * y;
        const int p = wave_m * 32 + mf * 16 + q4 * 4 + r4;
        out[(orow + p) * 32 + wave_n * 16 + j15] = f2bf(y);
      }
  }
  sa += __shfl_xor(sa, 16); sa += __shfl_xor(sa, 32);
  qa += __shfl_xor(qa, 16); qa += __shfl_xor(qa, 32);
  if (lane < 16) { red2[0][wv][lane] = sa; red2[1][wv][lane] = qa; }
  __syncthreads();
  if (tid < 64) {
    const int c = tid >> 1, jj = tid & 1;
    const int wn = c >> 4, li = c & 15;
    const float r = red2[jj][wn][li] + red2[jj][wn + 2][li];
    partial[((size_t)c * 2 + jj) * NPB2 + lin] = r;
  }
}

// ---- MFMA conv: 64px x 2 ROWS x COUT per block, PADDED affine LDS ---------
// 1D grid, XCD-aware decode (lin%8 = XCD): halo rows hit same-XCD L2
// (measured: FETCH 67.5 -> 35.2 MB). BN+lrelu fused into staging unpack.
template<int CIN, int COUT, bool WRITE_OUT, int MINW>
__global__ __launch_bounds__(256, MINW) void conv_mfma(
    const unsigned short* __restrict__ in, const unsigned short* __restrict__ wf,
    const float* __restrict__ bias,
    const float* __restrict__ bn_sc, const float* __restrict__ bn_sh,
    unsigned short* __restrict__ out, float* __restrict__ partial)
{
  constexpr int KC = CIN / 32;
  constexpr int NG = COUT / 16;
  constexpr int NF = COUT / 32;       // n-frags per wave (2 n-waves)
  constexpr int CH8 = CIN / 8;        // 16B chunks per pixel
  constexpr int CH8_LOG = (CH8 == 4) ? 2 : 3;
  constexpr int CPAD = CIN + 8;       // padded pixel stride (halfwords)
  constexpr int CHUNKS = 4 * 66 * CH8;

  const int tid = threadIdx.x, lane = tid & 63, wv = tid >> 6;
  const int wave_m = wv >> 1, wave_n = wv & 1;

  const int lin = blockIdx.x;
  const int xcd = lin & 7, slot = lin >> 3;
  const int b = slot >> 6;            // 0..7
  const int rem = slot & 63;          // 0..63
  const int h0 = ((xcd << 4) + (rem >> 2)) * 2;
  const int w0 = (rem & 3) * 64;
  const size_t inb = (size_t)b * HWSZ * CIN;

  __shared__ __align__(16) unsigned short lds[4 * 66 * CPAD];

  // stage 4 rows x 66 px, BN(scale/shift)+leakyReLU applied on unpack
  for (int c = tid; c < CHUNKS; c += 256) {
    const int r = c / (66 * CH8);
    const int rem2 = c - r * (66 * CH8);
    const int px = rem2 >> CH8_LOG, ck = rem2 & (CH8 - 1);
    const int hi = h0 + r - 1, wi = w0 - 1 + px;
    uint4 v = make_uint4(0u, 0u, 0u, 0u);
    if ((unsigned)hi < 256u && (unsigned)wi < 256u) {
      uint4 raw = *(const uint4*)&in[inb + ((size_t)hi * 256 + wi) * CIN + ck * 8];
      const float4 s0 = *(const float4*)&bn_sc[ck * 8];
      const float4 s1 = *(const float4*)&bn_sc[ck * 8 + 4];
      const float4 t0 = *(const float4*)&bn_sh[ck * 8];
      const float4 t1 = *(const float4*)&bn_sh[ck * 8 + 4];
      const float scs[8] = {s0.x, s0.y, s0.z, s0.w, s1.x, s1.y, s1.z, s1.w};
      const float shs[8] = {t0.x, t0.y, t0.z, t0.w, t1.x, t1.y, t1.z, t1.w};
      unsigned int* u = (unsigned int*)&raw;
      unsigned int* o = (unsigned int*)&v;
      #pragma unroll
      for (int p = 0; p < 4; ++p) {
        float a = bf2f((unsigned short)(u[p] & 0xffff));
        float d = bf2f((unsigned short)(u[p] >> 16));
        float ya = a * scs[2 * p] + shs[2 * p];
        float yd = d * scs[2 * p + 1] + shs[2 * p + 1];
        ya = fmaxf(ya, 0.01f * ya);
        yd = fmaxf(yd, 0.01f * yd);
        o[p] = pack2bf(ya, yd);
      }
    }
    *(uint4*)&lds[(r * 66 + px) * CPAD + ck * 8] = v;
  }
  __syncthreads();

  const int j15 = lane & 15, q4 = lane >> 4;
  const int base_px = wave_m * 32 + j15;
  const unsigned short* abase = &lds[base_px * CPAD + q4 * 8];

  floatx4 acc[2][2][NF];  // [row][mf][nf]
  #pragma unroll
  for (int rr = 0; rr < 2; ++rr)
    #pragma unroll
    for (int mf = 0; mf < 2; ++mf)
      #pragma unroll
      for (int nf = 0; nf < NF; ++nf) acc[rr][mf][nf] = (floatx4){0.f, 0.f, 0.f, 0.f};

  #pragma unroll
  for (int dh = 0; dh < 3; ++dh) {
    #pragma unroll
    for (int dw = 0; dw < 3; ++dw) {
      #pragma unroll
      for (int kc = 0; kc < KC; ++kc) {
        const int tap = dh * 3 + dw;
        short8 bg[NF];
        #pragma unroll
        for (int nf = 0; nf < NF; ++nf)
          bg[nf] = *(const short8*)&wf[((((tap * KC + kc) * NG) + wave_n * NF + nf) * 64 + lane) * 8];
        #pragma unroll
        for (int rr = 0; rr < 2; ++rr) {
          short8 a[2];
          #pragma unroll
          for (int mf = 0; mf < 2; ++mf)
            a[mf] = *(const short8*)&abase[((rr + dh) * 66 + dw + mf * 16) * CPAD + kc * 32];
          #pragma unroll
          for (int mf = 0; mf < 2; ++mf)
            #pragma unroll
            for (int nf = 0; nf < NF; ++nf)
              acc[rr][mf][nf] = __builtin_amdgcn_mfma_f32_16x16x32_bf16(a[mf], bg[nf], acc[rr][mf][nf], 0, 0, 0);
        }
      }
    }
  }

  // epilogue: +bias, per-wave stats over both rows, optional bf16 NHWC store
  float bv[NF], sa[NF], qa[NF];
  #pragma unroll
  for (int nf = 0; nf < NF; ++nf) {
    bv[nf] = bias[wave_n * (COUT / 2) + nf * 16 + j15];
    sa[nf] = 0.f; qa[nf] = 0.f;
  }
  #pragma unroll
  for (int rr = 0; rr < 2; ++rr) {
    const size_t orow = ((size_t)(b * 256 + (h0 + rr)) * 256 + w0);
    #pragma unroll
    for (int nf = 0; nf < NF; ++nf) {
      const int ch = wave_n * (COUT / 2) + nf * 16 + j15;
      #pragma unroll
      for (int mf = 0; mf < 2; ++mf)
        #pragma unroll
        for (int r4 = 0; r4 < 4; ++r4) {
          float y = acc[rr][mf][nf][r4] + bv[nf];
          sa[nf] += y; qa[nf] += y * y;
          if constexpr (WRITE_OUT) {
            const int p = wave_m * 32 + mf * 16 + q4 * 4 + r4;
            out[(orow + p) * COUT + ch] = f2bf(y);
          }
        }
    }
  }

  __syncthreads();
  float* red = (float*)lds;  // [4][NF][16] sums, then [4][NF][16] sumsq
  #pragma unroll
  for (int nf = 0; nf < NF; ++nf) {
    float s = sa[nf], q = qa[nf];
    s += __shfl_xor(s, 16); s += __shfl_xor(s, 32);
    q += __shfl_xor(q, 16); q += __shfl_xor(q, 32);
    if (lane < 16) {
      red[(wv * NF + nf) * 16 + lane] = s;
      red[4 * NF * 16 + (wv * NF + nf) * 16 + lane] = q;
    }
  }
  __syncthreads();
  if (tid < COUT) {
    const int wn = tid / (COUT / 2), rr = tid % (COUT / 2);
    const int nf = rr >> 4, li = rr & 15;
    float s = red[(wn * NF + nf) * 16 + li] + red[((wn + 2) * NF + nf) * 16 + li];
    float q = red[4 * NF * 16 + (wn * NF + nf) * 16 + li] +
              red[4 * NF * 16 + ((wn + 2) * NF + nf) * 16 + li];
    partial[((size_t)tid * 2 + 0) * NPB2 + lin] = s;
    partial[((size_t)tid * 2 + 1) * NPB2 + lin] = q;
  }
}

// ---- fold partials into scale/shift ---------------------------------------
__global__ __launch_bounds__(256) void reduce_stats(
    const float* __restrict__ partial, const float* __restrict__ gamma,
    const float* __restrict__ beta, float* __restrict__ scale,
    float* __restrict__ shift, int npb)
{
  const int c = blockIdx.x;
  float s = 0.f, q = 0.f;
  for (int i = threadIdx.x; i < npb; i += 256) {
    s += partial[((size_t)c * 2 + 0) * npb + i];
    q += partial[((size_t)c * 2 + 1) * npb + i];
  }
  #pragma unroll
  for (int o = 32; o > 0; o >>= 1) { s += __shfl_down(s, o); q += __shfl_down(q, o); }
  __shared__ float rs[4][2];
  const int lane = threadIdx.x & 63, wv = threadIdx.x >> 6;
  if (lane == 0) { rs[wv][0] = s; rs[wv][1] = q; }
  __syncthreads();
  if (threadIdx.x == 0) {
    s = rs[0][0] + rs[1][0] + rs[2][0] + rs[3][0];
    q = rs[0][1] + rs[1][1] + rs[2][1] + rs[3][1];
    const float N = (float)((size_t)BATCH * HWSZ);
    float mean = s / N;
    float var = q / N - mean * mean;
    float rstd = 1.0f / sqrtf(var + 1e-5f);
    float sc = gamma[c] * rstd;
    scale[c] = sc;
    shift[c] = beta[c] - mean * sc;
  }
}

// ---- fused outputs: patches (blocks 0..13) + encode (blocks 14..17) -------
// encode: conv3 at 8 pixels (n_xy) on RAW y2 (bn2+lrelu on read), bn3 at end.
__global__ __launch_bounds__(256) void outputs_kernel(
    const float* __restrict__ img, const int* __restrict__ axy,
    const int* __restrict__ pxy, const int* __restrict__ nxy,
    const unsigned short* __restrict__ y2, const float* __restrict__ wgt,
    const float* __restrict__ bias,
    const float* __restrict__ sc2, const float* __restrict__ sh2,
    const float* __restrict__ scale, const float* __restrict__ shift,
    float* __restrict__ out)
{
  if (blockIdx.x < 14) {
    const int i = blockIdx.x * 256 + threadIdx.x;
    if (i >= 3 * BATCH * 3 * 49) return;
    const int arr = i / 1176, r = i % 1176;
    const int b = r / 147, q = r % 147;
    const int c = q / 49, s = q % 49;
    const int ph = s / 7, pw = s % 7;
    const int* xy = (arr == 0) ? axy : ((arr == 1) ? pxy : nxy);
    const int x = xy[(b * 32 + 31) * 2 + 0];
    const int y = xy[(b * 32 + 31) * 2 + 1];
    out[i] = img[((size_t)(b * 3 + c) * HH + (x - 3 + ph)) * WW + (y - 3 + pw)];
  } else {
    const int b = (blockIdx.x - 14) * 2 + (threadIdx.x >> 7);
    const int co = threadIdx.x & 127;
    const int x = nxy[(b * 32 + 31) * 2 + 0];
    const int y = nxy[(b * 32 + 31) * 2 + 1];
    float acc = bias[co];
    for (int ci = 0; ci < 64; ++ci) {
      const float s2 = sc2[ci], h2 = sh2[ci];
      #pragma unroll
      for (int dh = -1; dh <= 1; ++dh)
        #pragma unroll
        for (int dw = -1; dw <= 1; ++dw) {
          float v = bf2f(y2[((size_t)(b * 256 + x + dh) * 256 + (y + dw)) * 64 + ci]);
          v = v * s2 + h2;
          v = fmaxf(v, 0.01f * v);
          acc = fmaf(wgt[((size_t)co * 64 + ci) * 9 + (dh + 1) * 3 + (dw + 1)], v, acc);
        }
    }
    const float yv = acc * scale[co] + shift[co];
    out[3528 + b * 128 + co] = fmaxf(yv, 0.01f * yv);
  }
}

extern "C" void kernel_launch(void* const* d_in, const int* in_sizes, int n_in,
                              void* d_out, int out_size, void* d_ws, size_t ws_size,
                              hipStream_t stream)
{
  const float* image = (const float*)d_in[0];
  const int* axy = (const int*)d_in[1];
  const int* pxy = (const int*)d_in[2];
  const int* nxy = (const int*)d_in[3];
  const float* c1w = (const float*)d_in[4];
  const float* c1b = (const float*)d_in[5];
  const float* g1 = (const float*)d_in[6];
  const float* b1 = (const float*)d_in[7];
  const float* c2w = (const float*)d_in[8];
  const float* c2b = (const float*)d_in[9];
  const float* g2 = (const float*)d_in[10];
  const float* b2 = (const float*)d_in[11];
  const float* c3w = (const float*)d_in[12];
  const float* c3b = (const float*)d_in[13];
  const float* g3 = (const float*)d_in[14];
  const float* b3 = (const float*)d_in[15];
  float* out = (float*)d_out;

  // workspace layout (~105 MB)
  unsigned short* zb1 = (unsigned short*)d_ws;            // raw y1, 16.78M bf16
  unsigned short* zb2 = zb1 + (size_t)8 * 32 * HWSZ;      // raw y2, 33.55M bf16
  unsigned short* wf2 = zb2 + (size_t)8 * 64 * HWSZ;      // 18432
  unsigned short* wf3 = wf2 + 18432;                      // 73728
  float* partial = (float*)(wf3 + 73728);                 // 128*2*4096 floats
  float* scale1 = partial + (size_t)128 * 2 * NPB2;
  float* shift1 = scale1 + 32;
  float* scale2 = shift1 + 32;
  float* shift2 = scale2 + 64;
  float* scale3 = shift2 + 64;
  float* shift3 = scale3 + 128;

  // conv1 via MFMA (blocks 0..4095) + wf2/wf3 prep (blocks 4096..4455)
  conv1_mfma<<<4456, 256, 0, stream>>>(
      image, c1w, c1b, zb1, partial, c2w, c3w, wf2, wf3);
  reduce_stats<<<32, 256, 0, stream>>>(partial, g1, b1, scale1, shift1, NPB2);

  // layer 2: 32 -> 64 (MFMA; bn1+lrelu fused in staging; raw y2 out + stats)
  conv_mfma<32, 64, true, 2><<<4096, 256, 0, stream>>>(
      zb1, wf2, c2b, scale1, shift1, zb2, partial);
  reduce_stats<<<64, 256, 0, stream>>>(partial, g2, b2, scale2, shift2, NPB2);

  // layer 3: 64 -> 128 (MFMA; bn2+lrelu fused in staging; stats only)
  conv_mfma<64, 128, false, 2><<<4096, 256, 0, stream>>>(
      zb2, wf3, c3b, scale2, shift2, nullptr, partial);
  reduce_stats<<<128, 256, 0, stream>>>(partial, g3, b3, scale3, shift3, NPB2);

  // outputs: patches + encode fused (bn2 on reads, bn3 at end)
  outputs_kernel<<<18, 256, 0, stream>>>(image, axy, pxy, nxy, zb2, c3w, c3b,
                                         scale2, shift2, scale3, shift3, out);
}

// Round 14
// 259.147 us; speedup vs baseline: 1.6810x; 1.0376x over previous
//
#include <hip/hip_runtime.h>
#include <math.h>

#define HH 256
#define WW 256
#define BATCH 8
#define HWSZ 65536
#define NPB2 4096  // partial slots (4096 blocks for all three convs)

typedef __attribute__((ext_vector_type(8))) short short8;
typedef __attribute__((ext_vector_type(4))) float floatx4;

// round-half-up bf16 pack: 2 VALU ops, max err 0.5 ulp
__device__ __forceinline__ unsigned short f2bf(float f) {
  union { float f; unsigned int u; } v; v.f = f;
  return (unsigned short)((v.u + 0x8000u) >> 16);
}
// pack two fp32 -> bf16x2 (lo=a, hi=d): 5 VALU ops
__device__ __forceinline__ unsigned int pack2bf(float a, float d) {
  union { float f; unsigned int u; } va, vd; va.f = a; vd.f = d;
  return ((va.u + 0x8000u) >> 16) | ((vd.u + 0x8000u) & 0xffff0000u);
}
__device__ __forceinline__ float bf2f(unsigned short u) {
  union { unsigned int u; float f; } v; v.u = ((unsigned int)u) << 16;
  return v.f;
}

// ---- conv1 as im2col MFMA (blocks 0..4095) + wf2/wf3 prep (4096..4455) ----
__global__ __launch_bounds__(256) void conv1_mfma(
    const float* __restrict__ img, const float* __restrict__ w1,
    const float* __restrict__ bias, unsigned short* __restrict__ out,
    float* __restrict__ partial,
    const float* __restrict__ w2, const float* __restrict__ w3,
    unsigned short* __restrict__ wf2, unsigned short* __restrict__ wf3)
{
  const int lin = blockIdx.x;
  if (lin >= 4096) {  // ---- prep path: 360 blocks cover 92160 elems ----
    int idx = (lin - 4096) * 256 + threadIdx.x;
    if (idx < 18432) {  // conv2: CIN=32, COUT=64, KC=1, NG=4
      const int j = idx & 7;
      const int lane = (idx >> 3) & 63;
      int rest = idx >> 9;
      const int ng = rest % 4;
      const int tap = rest / 4;
      const int cout = ng * 16 + (lane & 15);
      const int cin = ((lane >> 4) << 3) + j;
      wf2[idx] = f2bf(w2[((size_t)cout * 32 + cin) * 9 + tap]);
    } else {            // conv3: CIN=64, COUT=128, KC=2, NG=8
      idx -= 18432;
      if (idx >= 73728) return;
      const int j = idx & 7;
      const int lane = (idx >> 3) & 63;
      int rest = idx >> 9;
      const int ng = rest % 8; rest /= 8;
      const int kc = rest & 1;
      const int tap = rest >> 1;
      const int cout = ng * 16 + (lane & 15);
      const int cin = kc * 32 + ((lane >> 4) << 3) + j;
      wf3[idx] = f2bf(w3[((size_t)cout * 64 + cin) * 9 + tap]);
    }
    return;
  }

  const int tid = threadIdx.x, lane = tid & 63, wv = tid >> 6;
  const int wave_m = wv >> 1, wave_n = wv & 1;
  const int xcd = lin & 7, slot = lin >> 3;
  const int b = slot >> 6;
  const int rem = slot & 63;
  const int h0 = ((xcd << 4) + (rem >> 2)) * 2;
  const int w0 = (rem & 3) * 64;

  __shared__ __align__(16) unsigned short simg[4 * 66 * 4];  // [row][px][3ch+pad]
  __shared__ __align__(16) unsigned short swf[2 * 64 * 8];   // conv1 B-frags
  __shared__ float red2[2][4][16];                           // [s|q][wv][li]

  for (int t = tid; t < (4 * 66 * 4) / 2; t += 256)
    ((unsigned int*)simg)[t] = 0u;
  {
    const int t0 = tid * 4;
    #pragma unroll
    for (int u = 0; u < 4; ++u) {
      const int idx = t0 + u;
      const int j = idx & 7, l8 = (idx >> 3) & 63, nt = idx >> 9;
      const int k = ((l8 >> 4) << 3) + j;
      const int cout = nt * 16 + (l8 & 15);
      swf[idx] = (k < 27) ? f2bf(w1[cout * 27 + k]) : (unsigned short)0;
    }
  }
  __syncthreads();
  for (int t = tid; t < 792; t += 256) {
    const int ci = t / 264, r2 = t - ci * 264;
    const int r = r2 / 66, px = r2 - r * 66;
    const int hi = h0 + r - 1, wi = w0 + px - 1;
    if ((unsigned)hi < 256u && (unsigned)wi < 256u)
      simg[(r * 66 + px) * 4 + ci] =
          f2bf(img[((size_t)(b * 3 + ci) * 256 + hi) * 256 + wi]);
  }
  __syncthreads();

  const int j15 = lane & 15, q4 = lane >> 4;
  int off[8];
  #pragma unroll
  for (int j = 0; j < 8; ++j) {
    const int k = q4 * 8 + j;
    const int ci = k / 9, tap = k - ci * 9;
    const int dh = tap / 3, dw = tap - dh * 3;
    off[j] = (dh * 66 + dw) * 4 + ci;
  }
  const int base_px = wave_m * 32 + j15;
  const short8 bg = *(const short8*)&swf[(wave_n * 64 + lane) * 8];

  floatx4 acc[2][2];
  #pragma unroll
  for (int rr = 0; rr < 2; ++rr)
    #pragma unroll
    for (int mf = 0; mf < 2; ++mf) {
      acc[rr][mf] = (floatx4){0.f, 0.f, 0.f, 0.f};
      union { short8 v; unsigned short e[8]; } a;
      const int ab = (rr * 66 + base_px + mf * 16) * 4;
      #pragma unroll
      for (int j = 0; j < 8; ++j) a.e[j] = simg[ab + off[j]];
      acc[rr][mf] = __builtin_amdgcn_mfma_f32_16x16x32_bf16(a.v, bg, acc[rr][mf], 0, 0, 0);
    }

  float sa = 0.f, qa = 0.f;
  const float bv = bias[wave_n * 16 + j15];
  #pragma unroll
  for (int rr = 0; rr < 2; ++rr) {
    const size_t orow = ((size_t)(b * 256 + (h0 + rr)) * 256 + w0);
    #pragma unroll
    for (int mf = 0; mf < 2; ++mf)
      #pragma unroll
      for (int r4 = 0; r4 < 4; ++r4) {
        float y = acc[rr][mf][r4] + bv;
        sa += y; qa += y * y;
        const int p = wave_m * 32 + mf * 16 + q4 * 4 + r4;
        out[(orow + p) * 32 + wave_n * 16 + j15] = f2bf(y);
      }
  }
  sa += __shfl_xor(sa, 16); sa += __shfl_xor(sa, 32);
  qa += __shfl_xor(qa, 16); qa += __shfl_xor(qa, 32);
  if (lane < 16) { red2[0][wv][lane] = sa; red2[1][wv][lane] = qa; }
  __syncthreads();
  if (tid < 64) {
    const int c = tid >> 1, jj = tid & 1;
    const int wn = c >> 4, li = c & 15;
    const float r = red2[jj][wn][li] + red2[jj][wn + 2][li];
    partial[((size_t)c * 2 + jj) * NPB2 + lin] = r;
  }
}

// ---- MFMA conv: 64px x 2 ROWS x COUT per block, PADDED affine LDS ---------
// 1D grid, XCD-aware decode (lin%8 = XCD): halo rows hit same-XCD L2
// (measured: FETCH 67.5 -> 35.2 MB). BN+lrelu fused into staging unpack.
template<int CIN, int COUT, bool WRITE_OUT, int MINW>
__global__ __launch_bounds__(256, MINW) void conv_mfma(
    const unsigned short* __restrict__ in, const unsigned short* __restrict__ wf,
    const float* __restrict__ bias,
    const float* __restrict__ bn_sc, const float* __restrict__ bn_sh,
    unsigned short* __restrict__ out, float* __restrict__ partial)
{
  constexpr int KC = CIN / 32;
  constexpr int NG = COUT / 16;
  constexpr int NF = COUT / 32;
  constexpr int CH8 = CIN / 8;
  constexpr int CH8_LOG = (CH8 == 4) ? 2 : 3;
  constexpr int CPAD = CIN + 8;
  constexpr int CHUNKS = 4 * 66 * CH8;

  const int tid = threadIdx.x, lane = tid & 63, wv = tid >> 6;
  const int wave_m = wv >> 1, wave_n = wv & 1;

  const int lin = blockIdx.x;
  const int xcd = lin & 7, slot = lin >> 3;
  const int b = slot >> 6;
  const int rem = slot & 63;
  const int h0 = ((xcd << 4) + (rem >> 2)) * 2;
  const int w0 = (rem & 3) * 64;
  const size_t inb = (size_t)b * HWSZ * CIN;

  __shared__ __align__(16) unsigned short lds[4 * 66 * CPAD];

  for (int c = tid; c < CHUNKS; c += 256) {
    const int r = c / (66 * CH8);
    const int rem2 = c - r * (66 * CH8);
    const int px = rem2 >> CH8_LOG, ck = rem2 & (CH8 - 1);
    const int hi = h0 + r - 1, wi = w0 - 1 + px;
    uint4 v = make_uint4(0u, 0u, 0u, 0u);
    if ((unsigned)hi < 256u && (unsigned)wi < 256u) {
      uint4 raw = *(const uint4*)&in[inb + ((size_t)hi * 256 + wi) * CIN + ck * 8];
      const float4 s0 = *(const float4*)&bn_sc[ck * 8];
      const float4 s1 = *(const float4*)&bn_sc[ck * 8 + 4];
      const float4 t0 = *(const float4*)&bn_sh[ck * 8];
      const float4 t1 = *(const float4*)&bn_sh[ck * 8 + 4];
      const float scs[8] = {s0.x, s0.y, s0.z, s0.w, s1.x, s1.y, s1.z, s1.w};
      const float shs[8] = {t0.x, t0.y, t0.z, t0.w, t1.x, t1.y, t1.z, t1.w};
      unsigned int* u = (unsigned int*)&raw;
      unsigned int* o = (unsigned int*)&v;
      #pragma unroll
      for (int p = 0; p < 4; ++p) {
        float a = bf2f((unsigned short)(u[p] & 0xffff));
        float d = bf2f((unsigned short)(u[p] >> 16));
        float ya = a * scs[2 * p] + shs[2 * p];
        float yd = d * scs[2 * p + 1] + shs[2 * p + 1];
        ya = fmaxf(ya, 0.01f * ya);
        yd = fmaxf(yd, 0.01f * yd);
        o[p] = pack2bf(ya, yd);
      }
    }
    *(uint4*)&lds[(r * 66 + px) * CPAD + ck * 8] = v;
  }
  __syncthreads();

  const int j15 = lane & 15, q4 = lane >> 4;
  const int base_px = wave_m * 32 + j15;
  const unsigned short* abase = &lds[base_px * CPAD + q4 * 8];

  floatx4 acc[2][2][NF];
  #pragma unroll
  for (int rr = 0; rr < 2; ++rr)
    #pragma unroll
    for (int mf = 0; mf < 2; ++mf)
      #pragma unroll
      for (int nf = 0; nf < NF; ++nf) acc[rr][mf][nf] = (floatx4){0.f, 0.f, 0.f, 0.f};

  #pragma unroll
  for (int dh = 0; dh < 3; ++dh) {
    #pragma unroll
    for (int dw = 0; dw < 3; ++dw) {
      #pragma unroll
      for (int kc = 0; kc < KC; ++kc) {
        const int tap = dh * 3 + dw;
        short8 bg[NF];
        #pragma unroll
        for (int nf = 0; nf < NF; ++nf)
          bg[nf] = *(const short8*)&wf[((((tap * KC + kc) * NG) + wave_n * NF + nf) * 64 + lane) * 8];
        #pragma unroll
        for (int rr = 0; rr < 2; ++rr) {
          short8 a[2];
          #pragma unroll
          for (int mf = 0; mf < 2; ++mf)
            a[mf] = *(const short8*)&abase[((rr + dh) * 66 + dw + mf * 16) * CPAD + kc * 32];
          #pragma unroll
          for (int mf = 0; mf < 2; ++mf)
            #pragma unroll
            for (int nf = 0; nf < NF; ++nf)
              acc[rr][mf][nf] = __builtin_amdgcn_mfma_f32_16x16x32_bf16(a[mf], bg[nf], acc[rr][mf][nf], 0, 0, 0);
        }
      }
    }
  }

  float bv[NF], sa[NF], qa[NF];
  #pragma unroll
  for (int nf = 0; nf < NF; ++nf) {
    bv[nf] = bias[wave_n * (COUT / 2) + nf * 16 + j15];
    sa[nf] = 0.f; qa[nf] = 0.f;
  }
  #pragma unroll
  for (int rr = 0; rr < 2; ++rr) {
    const size_t orow = ((size_t)(b * 256 + (h0 + rr)) * 256 + w0);
    #pragma unroll
    for (int nf = 0; nf < NF; ++nf) {
      const int ch = wave_n * (COUT / 2) + nf * 16 + j15;
      #pragma unroll
      for (int mf = 0; mf < 2; ++mf)
        #pragma unroll
        for (int r4 = 0; r4 < 4; ++r4) {
          float y = acc[rr][mf][nf][r4] + bv[nf];
          sa[nf] += y; qa[nf] += y * y;
          if constexpr (WRITE_OUT) {
            const int p = wave_m * 32 + mf * 16 + q4 * 4 + r4;
            out[(orow + p) * COUT + ch] = f2bf(y);
          }
        }
    }
  }

  __syncthreads();
  float* red = (float*)lds;
  #pragma unroll
  for (int nf = 0; nf < NF; ++nf) {
    float s = sa[nf], q = qa[nf];
    s += __shfl_xor(s, 16); s += __shfl_xor(s, 32);
    q += __shfl_xor(q, 16); q += __shfl_xor(q, 32);
    if (lane < 16) {
      red[(wv * NF + nf) * 16 + lane] = s;
      red[4 * NF * 16 + (wv * NF + nf) * 16 + lane] = q;
    }
  }
  __syncthreads();
  if (tid < COUT) {
    const int wn = tid / (COUT / 2), rr = tid % (COUT / 2);
    const int nf = rr >> 4, li = rr & 15;
    float s = red[(wn * NF + nf) * 16 + li] + red[((wn + 2) * NF + nf) * 16 + li];
    float q = red[4 * NF * 16 + (wn * NF + nf) * 16 + li] +
              red[4 * NF * 16 + ((wn + 2) * NF + nf) * 16 + li];
    partial[((size_t)tid * 2 + 0) * NPB2 + lin] = s;
    partial[((size_t)tid * 2 + 1) * NPB2 + lin] = q;
  }
}

// ---- fold partials into scale/shift ---------------------------------------
__global__ __launch_bounds__(256) void reduce_stats(
    const float* __restrict__ partial, const float* __restrict__ gamma,
    const float* __restrict__ beta, float* __restrict__ scale,
    float* __restrict__ shift, int npb)
{
  const int c = blockIdx.x;
  float s = 0.f, q = 0.f;
  for (int i = threadIdx.x; i < npb; i += 256) {
    s += partial[((size_t)c * 2 + 0) * npb + i];
    q += partial[((size_t)c * 2 + 1) * npb + i];
  }
  #pragma unroll
  for (int o = 32; o > 0; o >>= 1) { s += __shfl_down(s, o); q += __shfl_down(q, o); }
  __shared__ float rs[4][2];
  const int lane = threadIdx.x & 63, wv = threadIdx.x >> 6;
  if (lane == 0) { rs[wv][0] = s; rs[wv][1] = q; }
  __syncthreads();
  if (threadIdx.x == 0) {
    s = rs[0][0] + rs[1][0] + rs[2][0] + rs[3][0];
    q = rs[0][1] + rs[1][1] + rs[2][1] + rs[3][1];
    const float N = (float)((size_t)BATCH * HWSZ);
    float mean = s / N;
    float var = q / N - mean * mean;
    float rstd = 1.0f / sqrtf(var + 1e-5f);
    float sc = gamma[c] * rstd;
    scale[c] = sc;
    shift[c] = beta[c] - mean * sc;
  }
}

// ---- fused outputs: patches (blocks 0..13) + encode (blocks 14..21) -------
// encode: one block per batch. 3x3x64 activation tile (bn2+lrelu applied)
// staged ONCE into LDS (was: 576 scalar global loads PER THREAD, broadcast
// by all 128 co-threads -- the latency sink). Weights read as per-thread
// contiguous float4 (L2-resident). bn3+lrelu at end.
__global__ __launch_bounds__(256) void outputs_kernel(
    const float* __restrict__ img, const int* __restrict__ axy,
    const int* __restrict__ pxy, const int* __restrict__ nxy,
    const unsigned short* __restrict__ y2, const float* __restrict__ wgt,
    const float* __restrict__ bias,
    const float* __restrict__ sc2, const float* __restrict__ sh2,
    const float* __restrict__ scale, const float* __restrict__ shift,
    float* __restrict__ out)
{
  if (blockIdx.x < 14) {
    const int i = blockIdx.x * 256 + threadIdx.x;
    if (i >= 3 * BATCH * 3 * 49) return;
    const int arr = i / 1176, r = i % 1176;
    const int b = r / 147, q = r % 147;
    const int c = q / 49, s = q % 49;
    const int ph = s / 7, pw = s % 7;
    const int* xy = (arr == 0) ? axy : ((arr == 1) ? pxy : nxy);
    const int x = xy[(b * 32 + 31) * 2 + 0];
    const int y = xy[(b * 32 + 31) * 2 + 1];
    out[i] = img[((size_t)(b * 3 + c) * HH + (x - 3 + ph)) * WW + (y - 3 + pw)];
  } else {
    const int b = blockIdx.x - 14;         // 0..7
    const int x = nxy[(b * 32 + 31) * 2 + 0];
    const int y = nxy[(b * 32 + 31) * 2 + 1];
    __shared__ float act[576];             // k = ci*9 + dh*3 + dw
    for (int t = threadIdx.x; t < 576; t += 256) {
      const int ci = t / 9, tap = t - ci * 9;
      const int dh = tap / 3, dw = tap - dh * 3;
      float v = bf2f(y2[((size_t)(b * 256 + (x + dh - 1)) * 256 + (y + dw - 1)) * 64 + ci]);
      v = v * sc2[ci] + sh2[ci];
      act[t] = fmaxf(v, 0.01f * v);
    }
    __syncthreads();
    if (threadIdx.x < 128) {
      const int co = threadIdx.x;
      float acc = bias[co];
      const float4* w4 = (const float4*)(wgt + (size_t)co * 576);
      #pragma unroll 9
      for (int kk = 0; kk < 144; ++kk) {
        const float4 wv = w4[kk];
        acc = fmaf(wv.x, act[4 * kk + 0], acc);
        acc = fmaf(wv.y, act[4 * kk + 1], acc);
        acc = fmaf(wv.z, act[4 * kk + 2], acc);
        acc = fmaf(wv.w, act[4 * kk + 3], acc);
      }
      const float yv = acc * scale[co] + shift[co];
      out[3528 + b * 128 + co] = fmaxf(yv, 0.01f * yv);
    }
  }
}

extern "C" void kernel_launch(void* const* d_in, const int* in_sizes, int n_in,
                              void* d_out, int out_size, void* d_ws, size_t ws_size,
                              hipStream_t stream)
{
  const float* image = (const float*)d_in[0];
  const int* axy = (const int*)d_in[1];
  const int* pxy = (const int*)d_in[2];
  const int* nxy = (const int*)d_in[3];
  const float* c1w = (const float*)d_in[4];
  const float* c1b = (const float*)d_in[5];
  const float* g1 = (const float*)d_in[6];
  const float* b1 = (const float*)d_in[7];
  const float* c2w = (const float*)d_in[8];
  const float* c2b = (const float*)d_in[9];
  const float* g2 = (const float*)d_in[10];
  const float* b2 = (const float*)d_in[11];
  const float* c3w = (const float*)d_in[12];
  const float* c3b = (const float*)d_in[13];
  const float* g3 = (const float*)d_in[14];
  const float* b3 = (const float*)d_in[15];
  float* out = (float*)d_out;

  // workspace layout (~105 MB)
  unsigned short* zb1 = (unsigned short*)d_ws;            // raw y1, 16.78M bf16
  unsigned short* zb2 = zb1 + (size_t)8 * 32 * HWSZ;      // raw y2, 33.55M bf16
  unsigned short* wf2 = zb2 + (size_t)8 * 64 * HWSZ;      // 18432
  unsigned short* wf3 = wf2 + 18432;                      // 73728
  float* partial = (float*)(wf3 + 73728);                 // 128*2*4096 floats
  float* scale1 = partial + (size_t)128 * 2 * NPB2;
  float* shift1 = scale1 + 32;
  float* scale2 = shift1 + 32;
  float* shift2 = scale2 + 64;
  float* scale3 = shift2 + 64;
  float* shift3 = scale3 + 128;

  // conv1 via MFMA (blocks 0..4095) + wf2/wf3 prep (blocks 4096..4455)
  conv1_mfma<<<4456, 256, 0, stream>>>(
      image, c1w, c1b, zb1, partial, c2w, c3w, wf2, wf3);
  reduce_stats<<<32, 256, 0, stream>>>(partial, g1, b1, scale1, shift1, NPB2);

  // layer 2: 32 -> 64 (MFMA; bn1+lrelu fused in staging; raw y2 out + stats)
  conv_mfma<32, 64, true, 2><<<4096, 256, 0, stream>>>(
      zb1, wf2, c2b, scale1, shift1, zb2, partial);
  reduce_stats<<<64, 256, 0, stream>>>(partial, g2, b2, scale2, shift2, NPB2);

  // layer 3: 64 -> 128 (MFMA; bn2+lrelu fused in staging; stats only)
  conv_mfma<64, 128, false, 2><<<4096, 256, 0, stream>>>(
      zb2, wf3, c3b, scale2, shift2, nullptr, partial);
  reduce_stats<<<128, 256, 0, stream>>>(partial, g3, b3, scale3, shift3, NPB2);

  // outputs: patches (0..13) + per-batch encode (14..21)
  outputs_kernel<<<22, 256, 0, stream>>>(image, axy, pxy, nxy, zb2, c3w, c3b,
                                         scale2, shift2, scale3, shift3, out);
}

// Round 15
// 248.196 us; speedup vs baseline: 1.7552x; 1.0441x over previous
//
#include <hip/hip_runtime.h>
#include <math.h>

#define HH 256
#define WW 256
#define BATCH 8
#define HWSZ 65536
#define BN_N 524288.0f  // BATCH*HWSZ
#define NSLOT 64        // stat-slot spreading factor

typedef __attribute__((ext_vector_type(8))) short short8;
typedef __attribute__((ext_vector_type(4))) float floatx4;

// round-half-up bf16 pack: 2 VALU ops, max err 0.5 ulp
__device__ __forceinline__ unsigned short f2bf(float f) {
  union { float f; unsigned int u; } v; v.f = f;
  return (unsigned short)((v.u + 0x8000u) >> 16);
}
// pack two fp32 -> bf16x2 (lo=a, hi=d): 5 VALU ops
__device__ __forceinline__ unsigned int pack2bf(float a, float d) {
  union { float f; unsigned int u; } va, vd; va.f = a; vd.f = d;
  return ((va.u + 0x8000u) >> 16) | ((vd.u + 0x8000u) & 0xffff0000u);
}
__device__ __forceinline__ float bf2f(unsigned short u) {
  union { unsigned int u; float f; } v; v.u = ((unsigned int)u) << 16;
  return v.f;
}

// ---- conv1 as im2col MFMA (blocks 0..4095) + wf2/wf3 prep (4096..4455) ----
// Stats -> atomicAdd into totals1[slot = lin&63][2][32] (64-way spread:
// 64 adds/address, vs R11's 4096/address which serialized).
__global__ __launch_bounds__(256) void conv1_mfma(
    const float* __restrict__ img, const float* __restrict__ w1,
    const float* __restrict__ bias, unsigned short* __restrict__ out,
    float* __restrict__ totals1,
    const float* __restrict__ w2, const float* __restrict__ w3,
    unsigned short* __restrict__ wf2, unsigned short* __restrict__ wf3)
{
  const int lin = blockIdx.x;
  if (lin >= 4096) {  // ---- prep path: 360 blocks cover 92160 elems ----
    int idx = (lin - 4096) * 256 + threadIdx.x;
    if (idx < 18432) {  // conv2: CIN=32, COUT=64, KC=1, NG=4
      const int j = idx & 7;
      const int lane = (idx >> 3) & 63;
      int rest = idx >> 9;
      const int ng = rest % 4;
      const int tap = rest / 4;
      const int cout = ng * 16 + (lane & 15);
      const int cin = ((lane >> 4) << 3) + j;
      wf2[idx] = f2bf(w2[((size_t)cout * 32 + cin) * 9 + tap]);
    } else {            // conv3: CIN=64, COUT=128, KC=2, NG=8
      idx -= 18432;
      if (idx >= 73728) return;
      const int j = idx & 7;
      const int lane = (idx >> 3) & 63;
      int rest = idx >> 9;
      const int ng = rest % 8; rest /= 8;
      const int kc = rest & 1;
      const int tap = rest >> 1;
      const int cout = ng * 16 + (lane & 15);
      const int cin = kc * 32 + ((lane >> 4) << 3) + j;
      wf3[idx] = f2bf(w3[((size_t)cout * 64 + cin) * 9 + tap]);
    }
    return;
  }

  const int tid = threadIdx.x, lane = tid & 63, wv = tid >> 6;
  const int wave_m = wv >> 1, wave_n = wv & 1;
  const int xcd = lin & 7, slot = lin >> 3;
  const int b = slot >> 6;
  const int rem = slot & 63;
  const int h0 = ((xcd << 4) + (rem >> 2)) * 2;
  const int w0 = (rem & 3) * 64;

  __shared__ __align__(16) unsigned short simg[4 * 66 * 4];  // [row][px][3ch+pad]
  __shared__ __align__(16) unsigned short swf[2 * 64 * 8];   // conv1 B-frags
  __shared__ float red2[2][4][16];                           // [s|q][wv][li]

  for (int t = tid; t < (4 * 66 * 4) / 2; t += 256)
    ((unsigned int*)simg)[t] = 0u;
  {
    const int t0 = tid * 4;
    #pragma unroll
    for (int u = 0; u < 4; ++u) {
      const int idx = t0 + u;
      const int j = idx & 7, l8 = (idx >> 3) & 63, nt = idx >> 9;
      const int k = ((l8 >> 4) << 3) + j;
      const int cout = nt * 16 + (l8 & 15);
      swf[idx] = (k < 27) ? f2bf(w1[cout * 27 + k]) : (unsigned short)0;
    }
  }
  __syncthreads();
  for (int t = tid; t < 792; t += 256) {
    const int ci = t / 264, r2 = t - ci * 264;
    const int r = r2 / 66, px = r2 - r * 66;
    const int hi = h0 + r - 1, wi = w0 + px - 1;
    if ((unsigned)hi < 256u && (unsigned)wi < 256u)
      simg[(r * 66 + px) * 4 + ci] =
          f2bf(img[((size_t)(b * 3 + ci) * 256 + hi) * 256 + wi]);
  }
  __syncthreads();

  const int j15 = lane & 15, q4 = lane >> 4;
  int off[8];
  #pragma unroll
  for (int j = 0; j < 8; ++j) {
    const int k = q4 * 8 + j;
    const int ci = k / 9, tap = k - ci * 9;
    const int dh = tap / 3, dw = tap - dh * 3;
    off[j] = (dh * 66 + dw) * 4 + ci;
  }
  const int base_px = wave_m * 32 + j15;
  const short8 bg = *(const short8*)&swf[(wave_n * 64 + lane) * 8];

  floatx4 acc[2][2];
  #pragma unroll
  for (int rr = 0; rr < 2; ++rr)
    #pragma unroll
    for (int mf = 0; mf < 2; ++mf) {
      acc[rr][mf] = (floatx4){0.f, 0.f, 0.f, 0.f};
      union { short8 v; unsigned short e[8]; } a;
      const int ab = (rr * 66 + base_px + mf * 16) * 4;
      #pragma unroll
      for (int j = 0; j < 8; ++j) a.e[j] = simg[ab + off[j]];
      acc[rr][mf] = __builtin_amdgcn_mfma_f32_16x16x32_bf16(a.v, bg, acc[rr][mf], 0, 0, 0);
    }

  float sa = 0.f, qa = 0.f;
  const float bv = bias[wave_n * 16 + j15];
  #pragma unroll
  for (int rr = 0; rr < 2; ++rr) {
    const size_t orow = ((size_t)(b * 256 + (h0 + rr)) * 256 + w0);
    #pragma unroll
    for (int mf = 0; mf < 2; ++mf)
      #pragma unroll
      for (int r4 = 0; r4 < 4; ++r4) {
        float y = acc[rr][mf][r4] + bv;
        sa += y; qa += y * y;
        const int p = wave_m * 32 + mf * 16 + q4 * 4 + r4;
        out[(orow + p) * 32 + wave_n * 16 + j15] = f2bf(y);
      }
  }
  sa += __shfl_xor(sa, 16); sa += __shfl_xor(sa, 32);
  qa += __shfl_xor(qa, 16); qa += __shfl_xor(qa, 32);
  if (lane < 16) { red2[0][wv][lane] = sa; red2[1][wv][lane] = qa; }
  __syncthreads();
  if (tid < 64) {
    const int c = tid >> 1, jj = tid & 1;
    const int wn = c >> 4, li = c & 15;
    const float r = red2[jj][wn][li] + red2[jj][wn + 2][li];
    atomicAdd(&totals1[(((size_t)(lin & (NSLOT - 1)) * 2 + jj)) * 32 + c], r);
  }
}

// ---- MFMA conv: 64px x 2 ROWS x COUT per block, PADDED affine LDS ---------
// Input-layer BN folded inline from totals_in (64 slots) + gamma/beta ->
// LDS scale/shift (~128 indep L2-hot loads, hidden). XCD-aware decode.
// Own stats -> 64-way-spread atomicAdd into totals_out.
template<int CIN, int COUT, bool WRITE_OUT, int MINW>
__global__ __launch_bounds__(256, MINW) void conv_mfma(
    const unsigned short* __restrict__ in, const unsigned short* __restrict__ wf,
    const float* __restrict__ bias,
    const float* __restrict__ totals_in, const float* __restrict__ gamma_in,
    const float* __restrict__ beta_in,
    unsigned short* __restrict__ out, float* __restrict__ totals_out)
{
  constexpr int KC = CIN / 32;
  constexpr int NG = COUT / 16;
  constexpr int NF = COUT / 32;
  constexpr int CH8 = CIN / 8;
  constexpr int CH8_LOG = (CH8 == 4) ? 2 : 3;
  constexpr int CPAD = CIN + 8;
  constexpr int CHUNKS = 4 * 66 * CH8;

  const int tid = threadIdx.x, lane = tid & 63, wv = tid >> 6;
  const int wave_m = wv >> 1, wave_n = wv & 1;

  const int lin = blockIdx.x;
  const int xcd = lin & 7, slot = lin >> 3;
  const int b = slot >> 6;
  const int rem = slot & 63;
  const int h0 = ((xcd << 4) + (rem >> 2)) * 2;
  const int w0 = (rem & 3) * 64;
  const size_t inb = (size_t)b * HWSZ * CIN;

  __shared__ __align__(16) unsigned short lds[4 * 66 * CPAD];
  __shared__ __align__(16) float scsh[2][CIN];

  // fold input-layer BN from 64 stat slots (replaces reduce_stats dispatch)
  if (tid < CIN) {
    float s = 0.f, q = 0.f;
    #pragma unroll 8
    for (int i = 0; i < NSLOT; ++i) {
      s += totals_in[((size_t)i * 2 + 0) * CIN + tid];
      q += totals_in[((size_t)i * 2 + 1) * CIN + tid];
    }
    const float mean = s / BN_N;
    const float var = q / BN_N - mean * mean;
    const float rstd = rsqrtf(var + 1e-5f);
    const float sc = gamma_in[tid] * rstd;
    scsh[0][tid] = sc;
    scsh[1][tid] = beta_in[tid] - mean * sc;
  }
  __syncthreads();

  for (int c = tid; c < CHUNKS; c += 256) {
    const int r = c / (66 * CH8);
    const int rem2 = c - r * (66 * CH8);
    const int px = rem2 >> CH8_LOG, ck = rem2 & (CH8 - 1);
    const int hi = h0 + r - 1, wi = w0 - 1 + px;
    uint4 v = make_uint4(0u, 0u, 0u, 0u);
    if ((unsigned)hi < 256u && (unsigned)wi < 256u) {
      uint4 raw = *(const uint4*)&in[inb + ((size_t)hi * 256 + wi) * CIN + ck * 8];
      const float4 s0 = *(const float4*)&scsh[0][ck * 8];
      const float4 s1 = *(const float4*)&scsh[0][ck * 8 + 4];
      const float4 t0 = *(const float4*)&scsh[1][ck * 8];
      const float4 t1 = *(const float4*)&scsh[1][ck * 8 + 4];
      const float scs[8] = {s0.x, s0.y, s0.z, s0.w, s1.x, s1.y, s1.z, s1.w};
      const float shs[8] = {t0.x, t0.y, t0.z, t0.w, t1.x, t1.y, t1.z, t1.w};
      unsigned int* u = (unsigned int*)&raw;
      unsigned int* o = (unsigned int*)&v;
      #pragma unroll
      for (int p = 0; p < 4; ++p) {
        float a = bf2f((unsigned short)(u[p] & 0xffff));
        float d = bf2f((unsigned short)(u[p] >> 16));
        float ya = a * scs[2 * p] + shs[2 * p];
        float yd = d * scs[2 * p + 1] + shs[2 * p + 1];
        ya = fmaxf(ya, 0.01f * ya);
        yd = fmaxf(yd, 0.01f * yd);
        o[p] = pack2bf(ya, yd);
      }
    }
    *(uint4*)&lds[(r * 66 + px) * CPAD + ck * 8] = v;
  }
  __syncthreads();

  const int j15 = lane & 15, q4 = lane >> 4;
  const int base_px = wave_m * 32 + j15;
  const unsigned short* abase = &lds[base_px * CPAD + q4 * 8];

  floatx4 acc[2][2][NF];
  #pragma unroll
  for (int rr = 0; rr < 2; ++rr)
    #pragma unroll
    for (int mf = 0; mf < 2; ++mf)
      #pragma unroll
      for (int nf = 0; nf < NF; ++nf) acc[rr][mf][nf] = (floatx4){0.f, 0.f, 0.f, 0.f};

  #pragma unroll
  for (int dh = 0; dh < 3; ++dh) {
    #pragma unroll
    for (int dw = 0; dw < 3; ++dw) {
      #pragma unroll
      for (int kc = 0; kc < KC; ++kc) {
        const int tap = dh * 3 + dw;
        short8 bg[NF];
        #pragma unroll
        for (int nf = 0; nf < NF; ++nf)
          bg[nf] = *(const short8*)&wf[((((tap * KC + kc) * NG) + wave_n * NF + nf) * 64 + lane) * 8];
        #pragma unroll
        for (int rr = 0; rr < 2; ++rr) {
          short8 a[2];
          #pragma unroll
          for (int mf = 0; mf < 2; ++mf)
            a[mf] = *(const short8*)&abase[((rr + dh) * 66 + dw + mf * 16) * CPAD + kc * 32];
          #pragma unroll
          for (int mf = 0; mf < 2; ++mf)
            #pragma unroll
            for (int nf = 0; nf < NF; ++nf)
              acc[rr][mf][nf] = __builtin_amdgcn_mfma_f32_16x16x32_bf16(a[mf], bg[nf], acc[rr][mf][nf], 0, 0, 0);
        }
      }
    }
  }

  float bv[NF], sa[NF], qa[NF];
  #pragma unroll
  for (int nf = 0; nf < NF; ++nf) {
    bv[nf] = bias[wave_n * (COUT / 2) + nf * 16 + j15];
    sa[nf] = 0.f; qa[nf] = 0.f;
  }
  #pragma unroll
  for (int rr = 0; rr < 2; ++rr) {
    const size_t orow = ((size_t)(b * 256 + (h0 + rr)) * 256 + w0);
    #pragma unroll
    for (int nf = 0; nf < NF; ++nf) {
      const int ch = wave_n * (COUT / 2) + nf * 16 + j15;
      #pragma unroll
      for (int mf = 0; mf < 2; ++mf)
        #pragma unroll
        for (int r4 = 0; r4 < 4; ++r4) {
          float y = acc[rr][mf][nf][r4] + bv[nf];
          sa[nf] += y; qa[nf] += y * y;
          if constexpr (WRITE_OUT) {
            const int p = wave_m * 32 + mf * 16 + q4 * 4 + r4;
            out[(orow + p) * COUT + ch] = f2bf(y);
          }
        }
    }
  }

  __syncthreads();
  float* red = (float*)lds;
  #pragma unroll
  for (int nf = 0; nf < NF; ++nf) {
    float s = sa[nf], q = qa[nf];
    s += __shfl_xor(s, 16); s += __shfl_xor(s, 32);
    q += __shfl_xor(q, 16); q += __shfl_xor(q, 32);
    if (lane < 16) {
      red[(wv * NF + nf) * 16 + lane] = s;
      red[4 * NF * 16 + (wv * NF + nf) * 16 + lane] = q;
    }
  }
  __syncthreads();
  if (tid < COUT) {
    const int wn = tid / (COUT / 2), rr = tid % (COUT / 2);
    const int nf = rr >> 4, li = rr & 15;
    float s = red[(wn * NF + nf) * 16 + li] + red[((wn + 2) * NF + nf) * 16 + li];
    float q = red[4 * NF * 16 + (wn * NF + nf) * 16 + li] +
              red[4 * NF * 16 + ((wn + 2) * NF + nf) * 16 + li];
    const int sl = lin & (NSLOT - 1);
    atomicAdd(&totals_out[((size_t)sl * 2 + 0) * COUT + tid], s);
    atomicAdd(&totals_out[((size_t)sl * 2 + 1) * COUT + tid], q);
  }
}

// ---- fused outputs: patches (blocks 0..13) + encode (blocks 14..21) -------
// encode: one block per batch; bn2/bn3 folded inline from 64-slot totals;
// 3x3x64 activation tile staged once in LDS; float4 weight loads.
__global__ __launch_bounds__(256) void outputs_kernel(
    const float* __restrict__ img, const int* __restrict__ axy,
    const int* __restrict__ pxy, const int* __restrict__ nxy,
    const unsigned short* __restrict__ y2, const float* __restrict__ wgt,
    const float* __restrict__ bias,
    const float* __restrict__ totals2, const float* __restrict__ g2,
    const float* __restrict__ b2v,
    const float* __restrict__ totals3, const float* __restrict__ g3,
    const float* __restrict__ b3v,
    float* __restrict__ out)
{
  if (blockIdx.x < 14) {
    const int i = blockIdx.x * 256 + threadIdx.x;
    if (i >= 3 * BATCH * 3 * 49) return;
    const int arr = i / 1176, r = i % 1176;
    const int b = r / 147, q = r % 147;
    const int c = q / 49, s = q % 49;
    const int ph = s / 7, pw = s % 7;
    const int* xy = (arr == 0) ? axy : ((arr == 1) ? pxy : nxy);
    const int x = xy[(b * 32 + 31) * 2 + 0];
    const int y = xy[(b * 32 + 31) * 2 + 1];
    out[i] = img[((size_t)(b * 3 + c) * HH + (x - 3 + ph)) * WW + (y - 3 + pw)];
  } else {
    const int b = blockIdx.x - 14;         // 0..7
    const int x = nxy[(b * 32 + 31) * 2 + 0];
    const int y = nxy[(b * 32 + 31) * 2 + 1];
    __shared__ float sc2[2][64], sc3[2][128];
    __shared__ float act[576];             // k = ci*9 + dh*3 + dw
    if (threadIdx.x < 64) {
      float s = 0.f, q = 0.f;
      for (int i = 0; i < NSLOT; ++i) {
        s += totals2[((size_t)i * 2 + 0) * 64 + threadIdx.x];
        q += totals2[((size_t)i * 2 + 1) * 64 + threadIdx.x];
      }
      const float mean = s / BN_N;
      const float var = q / BN_N - mean * mean;
      const float rstd = rsqrtf(var + 1e-5f);
      const float sc = g2[threadIdx.x] * rstd;
      sc2[0][threadIdx.x] = sc;
      sc2[1][threadIdx.x] = b2v[threadIdx.x] - mean * sc;
    } else if (threadIdx.x >= 128) {
      const int c = threadIdx.x - 128;
      float s = 0.f, q = 0.f;
      for (int i = 0; i < NSLOT; ++i) {
        s += totals3[((size_t)i * 2 + 0) * 128 + c];
        q += totals3[((size_t)i * 2 + 1) * 128 + c];
      }
      const float mean = s / BN_N;
      const float var = q / BN_N - mean * mean;
      const float rstd = rsqrtf(var + 1e-5f);
      const float sc = g3[c] * rstd;
      sc3[0][c] = sc;
      sc3[1][c] = b3v[c] - mean * sc;
    }
    __syncthreads();
    for (int t = threadIdx.x; t < 576; t += 256) {
      const int ci = t / 9, tap = t - ci * 9;
      const int dh = tap / 3, dw = tap - dh * 3;
      float v = bf2f(y2[((size_t)(b * 256 + (x + dh - 1)) * 256 + (y + dw - 1)) * 64 + ci]);
      v = v * sc2[0][ci] + sc2[1][ci];
      act[t] = fmaxf(v, 0.01f * v);
    }
    __syncthreads();
    if (threadIdx.x < 128) {
      const int co = threadIdx.x;
      float acc = bias[co];
      const float4* w4 = (const float4*)(wgt + (size_t)co * 576);
      #pragma unroll 9
      for (int kk = 0; kk < 144; ++kk) {
        const float4 wv = w4[kk];
        acc = fmaf(wv.x, act[4 * kk + 0], acc);
        acc = fmaf(wv.y, act[4 * kk + 1], acc);
        acc = fmaf(wv.z, act[4 * kk + 2], acc);
        acc = fmaf(wv.w, act[4 * kk + 3], acc);
      }
      const float yv = acc * sc3[0][co] + sc3[1][co];
      out[3528 + b * 128 + co] = fmaxf(yv, 0.01f * yv);
    }
  }
}

extern "C" void kernel_launch(void* const* d_in, const int* in_sizes, int n_in,
                              void* d_out, int out_size, void* d_ws, size_t ws_size,
                              hipStream_t stream)
{
  const float* image = (const float*)d_in[0];
  const int* axy = (const int*)d_in[1];
  const int* pxy = (const int*)d_in[2];
  const int* nxy = (const int*)d_in[3];
  const float* c1w = (const float*)d_in[4];
  const float* c1b = (const float*)d_in[5];
  const float* g1 = (const float*)d_in[6];
  const float* b1 = (const float*)d_in[7];
  const float* c2w = (const float*)d_in[8];
  const float* c2b = (const float*)d_in[9];
  const float* g2 = (const float*)d_in[10];
  const float* b2 = (const float*)d_in[11];
  const float* c3w = (const float*)d_in[12];
  const float* c3b = (const float*)d_in[13];
  const float* g3 = (const float*)d_in[14];
  const float* b3 = (const float*)d_in[15];
  float* out = (float*)d_out;

  // workspace layout (~101 MB)
  unsigned short* zb1 = (unsigned short*)d_ws;            // raw y1, 16.78M bf16
  unsigned short* zb2 = zb1 + (size_t)8 * 32 * HWSZ;      // raw y2, 33.55M bf16
  unsigned short* wf2 = zb2 + (size_t)8 * 64 * HWSZ;      // 18432
  unsigned short* wf3 = wf2 + 18432;                      // 73728
  float* totals1 = (float*)(wf3 + 73728);                 // 64*2*32  = 4096
  float* totals2 = totals1 + (size_t)NSLOT * 2 * 32;      // 64*2*64  = 8192
  float* totals3 = totals2 + (size_t)NSLOT * 2 * 64;      // 64*2*128 = 16384

  // zero the 64-slot stat accumulators (28672 floats)
  hipMemsetAsync(totals1, 0, (size_t)NSLOT * 2 * (32 + 64 + 128) * sizeof(float),
                 stream);

  // conv1 via MFMA (blocks 0..4095) + wf2/wf3 prep (blocks 4096..4455)
  conv1_mfma<<<4456, 256, 0, stream>>>(
      image, c1w, c1b, zb1, totals1, c2w, c3w, wf2, wf3);

  // layer 2: 32 -> 64 (MFMA; bn1 folded inline; raw y2 out + slot stats)
  conv_mfma<32, 64, true, 2><<<4096, 256, 0, stream>>>(
      zb1, wf2, c2b, totals1, g1, b1, zb2, totals2);

  // layer 3: 64 -> 128 (MFMA; bn2 folded inline; stats only)
  conv_mfma<64, 128, false, 2><<<4096, 256, 0, stream>>>(
      zb2, wf3, c3b, totals2, g2, b2, nullptr, totals3);

  // outputs: patches (0..13) + per-batch encode (14..21), bn folds inline
  outputs_kernel<<<22, 256, 0, stream>>>(image, axy, pxy, nxy, zb2, c3w, c3b,
                                         totals2, g2, b2, totals3, g3, b3, out);
}

// Round 16
// 241.202 us; speedup vs baseline: 1.8061x; 1.0290x over previous
//
#include <hip/hip_runtime.h>
#include <math.h>

#define HH 256
#define WW 256
#define BATCH 8
#define HWSZ 65536
#define BN_N 524288.0f  // BATCH*HWSZ
#define NSLOT 64        // stat-slot spreading factor

typedef __attribute__((ext_vector_type(8))) short short8;
typedef __attribute__((ext_vector_type(4))) float floatx4;

// round-half-up bf16 pack: 2 VALU ops, max err 0.5 ulp
__device__ __forceinline__ unsigned short f2bf(float f) {
  union { float f; unsigned int u; } v; v.f = f;
  return (unsigned short)((v.u + 0x8000u) >> 16);
}
// pack two fp32 -> bf16x2 (lo=a, hi=d): 5 VALU ops
__device__ __forceinline__ unsigned int pack2bf(float a, float d) {
  union { float f; unsigned int u; } va, vd; va.f = a; vd.f = d;
  return ((va.u + 0x8000u) >> 16) | ((vd.u + 0x8000u) & 0xffff0000u);
}
__device__ __forceinline__ float bf2f(unsigned short u) {
  union { unsigned int u; float f; } v; v.u = ((unsigned int)u) << 16;
  return v.f;
}

// ---- conv1 as im2col MFMA (blocks 0..4095) + wf2/wf3 prep (4096..4455) ----
__global__ __launch_bounds__(256) void conv1_mfma(
    const float* __restrict__ img, const float* __restrict__ w1,
    const float* __restrict__ bias, unsigned short* __restrict__ out,
    float* __restrict__ totals1,
    const float* __restrict__ w2, const float* __restrict__ w3,
    unsigned short* __restrict__ wf2, unsigned short* __restrict__ wf3)
{
  const int lin = blockIdx.x;
  if (lin >= 4096) {  // ---- prep path: 360 blocks cover 92160 elems ----
    int idx = (lin - 4096) * 256 + threadIdx.x;
    if (idx < 18432) {  // conv2: CIN=32, COUT=64, KC=1, NG=4
      const int j = idx & 7;
      const int lane = (idx >> 3) & 63;
      int rest = idx >> 9;
      const int ng = rest % 4;
      const int tap = rest / 4;
      const int cout = ng * 16 + (lane & 15);
      const int cin = ((lane >> 4) << 3) + j;
      wf2[idx] = f2bf(w2[((size_t)cout * 32 + cin) * 9 + tap]);
    } else {            // conv3: CIN=64, COUT=128, KC=2, NG=8
      idx -= 18432;
      if (idx >= 73728) return;
      const int j = idx & 7;
      const int lane = (idx >> 3) & 63;
      int rest = idx >> 9;
      const int ng = rest % 8; rest /= 8;
      const int kc = rest & 1;
      const int tap = rest >> 1;
      const int cout = ng * 16 + (lane & 15);
      const int cin = kc * 32 + ((lane >> 4) << 3) + j;
      wf3[idx] = f2bf(w3[((size_t)cout * 64 + cin) * 9 + tap]);
    }
    return;
  }

  const int tid = threadIdx.x, lane = tid & 63, wv = tid >> 6;
  const int wave_m = wv >> 1, wave_n = wv & 1;
  const int xcd = lin & 7, slot = lin >> 3;
  const int b = slot >> 6;
  const int rem = slot & 63;
  const int h0 = ((xcd << 4) + (rem >> 2)) * 2;
  const int w0 = (rem & 3) * 64;

  __shared__ __align__(16) unsigned short simg[4 * 66 * 4];  // [row][px][3ch+pad]
  __shared__ __align__(16) unsigned short swf[2 * 64 * 8];   // conv1 B-frags
  __shared__ float red2[2][4][16];                           // [s|q][wv][li]

  for (int t = tid; t < (4 * 66 * 4) / 2; t += 256)
    ((unsigned int*)simg)[t] = 0u;
  {
    const int t0 = tid * 4;
    #pragma unroll
    for (int u = 0; u < 4; ++u) {
      const int idx = t0 + u;
      const int j = idx & 7, l8 = (idx >> 3) & 63, nt = idx >> 9;
      const int k = ((l8 >> 4) << 3) + j;
      const int cout = nt * 16 + (l8 & 15);
      swf[idx] = (k < 27) ? f2bf(w1[cout * 27 + k]) : (unsigned short)0;
    }
  }
  __syncthreads();
  for (int t = tid; t < 792; t += 256) {
    const int ci = t / 264, r2 = t - ci * 264;
    const int r = r2 / 66, px = r2 - r * 66;
    const int hi = h0 + r - 1, wi = w0 + px - 1;
    if ((unsigned)hi < 256u && (unsigned)wi < 256u)
      simg[(r * 66 + px) * 4 + ci] =
          f2bf(img[((size_t)(b * 3 + ci) * 256 + hi) * 256 + wi]);
  }
  __syncthreads();

  const int j15 = lane & 15, q4 = lane >> 4;
  int off[8];
  #pragma unroll
  for (int j = 0; j < 8; ++j) {
    const int k = q4 * 8 + j;
    const int ci = k / 9, tap = k - ci * 9;
    const int dh = tap / 3, dw = tap - dh * 3;
    off[j] = (dh * 66 + dw) * 4 + ci;
  }
  const int base_px = wave_m * 32 + j15;
  const short8 bg = *(const short8*)&swf[(wave_n * 64 + lane) * 8];

  floatx4 acc[2][2];
  #pragma unroll
  for (int rr = 0; rr < 2; ++rr)
    #pragma unroll
    for (int mf = 0; mf < 2; ++mf) {
      acc[rr][mf] = (floatx4){0.f, 0.f, 0.f, 0.f};
      union { short8 v; unsigned short e[8]; } a;
      const int ab = (rr * 66 + base_px + mf * 16) * 4;
      #pragma unroll
      for (int j = 0; j < 8; ++j) a.e[j] = simg[ab + off[j]];
      acc[rr][mf] = __builtin_amdgcn_mfma_f32_16x16x32_bf16(a.v, bg, acc[rr][mf], 0, 0, 0);
    }

  float sa = 0.f, qa = 0.f;
  const float bv = bias[wave_n * 16 + j15];
  #pragma unroll
  for (int rr = 0; rr < 2; ++rr) {
    const size_t orow = ((size_t)(b * 256 + (h0 + rr)) * 256 + w0);
    #pragma unroll
    for (int mf = 0; mf < 2; ++mf)
      #pragma unroll
      for (int r4 = 0; r4 < 4; ++r4) {
        float y = acc[rr][mf][r4] + bv;
        sa += y; qa += y * y;
        const int p = wave_m * 32 + mf * 16 + q4 * 4 + r4;
        out[(orow + p) * 32 + wave_n * 16 + j15] = f2bf(y);
      }
  }
  sa += __shfl_xor(sa, 16); sa += __shfl_xor(sa, 32);
  qa += __shfl_xor(qa, 16); qa += __shfl_xor(qa, 32);
  if (lane < 16) { red2[0][wv][lane] = sa; red2[1][wv][lane] = qa; }
  __syncthreads();
  if (tid < 64) {
    const int c = tid >> 1, jj = tid & 1;
    const int wn = c >> 4, li = c & 15;
    const float r = red2[jj][wn][li] + red2[jj][wn + 2][li];
    atomicAdd(&totals1[(((size_t)(lin & (NSLOT - 1)) * 2 + jj)) * 32 + c], r);
  }
}

// ---- MFMA conv: 64px x 2 ROWS x COUT per block, PADDED affine LDS ---------
// BN fold parallelized over all 256 threads (G slot-groups -> LDS partials).
// Staging: thread owns a FIXED 16B channel-chunk ck, iterates row-major
// pixel slots -> scale/shift registers loaded once; LDS offset has no div.
template<int CIN, int COUT, bool WRITE_OUT, int MINW>
__global__ __launch_bounds__(256, MINW) void conv_mfma(
    const unsigned short* __restrict__ in, const unsigned short* __restrict__ wf,
    const float* __restrict__ bias,
    const float* __restrict__ totals_in, const float* __restrict__ gamma_in,
    const float* __restrict__ beta_in,
    unsigned short* __restrict__ out, float* __restrict__ totals_out)
{
  constexpr int KC = CIN / 32;
  constexpr int NG = COUT / 16;
  constexpr int NF = COUT / 32;
  constexpr int CH8 = CIN / 8;
  constexpr int CH8_LOG = (CH8 == 4) ? 2 : 3;
  constexpr int CPAD = CIN + 8;
  constexpr int GRP = 256 / CIN;        // fold groups
  constexpr int SPG = NSLOT / GRP;      // slots per group

  const int tid = threadIdx.x, lane = tid & 63, wv = tid >> 6;
  const int wave_m = wv >> 1, wave_n = wv & 1;

  const int lin = blockIdx.x;
  const int xcd = lin & 7, slot = lin >> 3;
  const int b = slot >> 6;
  const int rem = slot & 63;
  const int h0 = ((xcd << 4) + (rem >> 2)) * 2;
  const int w0 = (rem & 3) * 64;
  const size_t inb = (size_t)b * HWSZ * CIN;

  __shared__ __align__(16) unsigned short lds[4 * 66 * CPAD];
  __shared__ __align__(16) float scsh[2][CIN];

  // parallel BN fold: 256 threads cover NSLOT slots in GRP groups
  {
    const int c = tid % CIN, g = tid / CIN;
    float ps = 0.f, pq = 0.f;
    #pragma unroll
    for (int i = 0; i < SPG; ++i) {
      const int sl = g * SPG + i;
      ps += totals_in[((size_t)sl * 2 + 0) * CIN + c];
      pq += totals_in[((size_t)sl * 2 + 1) * CIN + c];
    }
    float* pf = (float*)lds;  // [2][GRP][CIN] partials (staging overwrites later)
    pf[(0 * GRP + g) * CIN + c] = ps;
    pf[(1 * GRP + g) * CIN + c] = pq;
    __syncthreads();
    if (tid < CIN) {
      float s = 0.f, q = 0.f;
      #pragma unroll
      for (int g2 = 0; g2 < GRP; ++g2) {
        s += pf[(0 * GRP + g2) * CIN + tid];
        q += pf[(1 * GRP + g2) * CIN + tid];
      }
      const float mean = s / BN_N;
      const float var = q / BN_N - mean * mean;
      const float rstd = rsqrtf(var + 1e-5f);
      const float sc = gamma_in[tid] * rstd;
      scsh[0][tid] = sc;
      scsh[1][tid] = beta_in[tid] - mean * sc;
    }
    __syncthreads();
  }

  // staging: fixed ck per thread; scale/shift regs loaded ONCE
  {
    const int ck = tid & (CH8 - 1);
    const float4 s0 = *(const float4*)&scsh[0][ck * 8];
    const float4 s1 = *(const float4*)&scsh[0][ck * 8 + 4];
    const float4 t0 = *(const float4*)&scsh[1][ck * 8];
    const float4 t1 = *(const float4*)&scsh[1][ck * 8 + 4];
    const float scs[8] = {s0.x, s0.y, s0.z, s0.w, s1.x, s1.y, s1.z, s1.w};
    const float shs[8] = {t0.x, t0.y, t0.z, t0.w, t1.x, t1.y, t1.z, t1.w};
    for (int rpx = tid >> CH8_LOG; rpx < 264; rpx += 256 >> CH8_LOG) {
      const int r = rpx / 66, px = rpx - r * 66;
      const int hi = h0 + r - 1, wi = w0 - 1 + px;
      uint4 v = make_uint4(0u, 0u, 0u, 0u);
      if ((unsigned)hi < 256u && (unsigned)wi < 256u) {
        uint4 raw = *(const uint4*)&in[inb + ((size_t)hi * 256 + wi) * CIN + ck * 8];
        unsigned int* u = (unsigned int*)&raw;
        unsigned int* o = (unsigned int*)&v;
        #pragma unroll
        for (int p = 0; p < 4; ++p) {
          float a = bf2f((unsigned short)(u[p] & 0xffff));
          float d = bf2f((unsigned short)(u[p] >> 16));
          float ya = a * scs[2 * p] + shs[2 * p];
          float yd = d * scs[2 * p + 1] + shs[2 * p + 1];
          ya = fmaxf(ya, 0.01f * ya);
          yd = fmaxf(yd, 0.01f * yd);
          o[p] = pack2bf(ya, yd);
        }
      }
      *(uint4*)&lds[rpx * CPAD + ck * 8] = v;
    }
  }
  __syncthreads();

  const int j15 = lane & 15, q4 = lane >> 4;
  const int base_px = wave_m * 32 + j15;
  const unsigned short* abase = &lds[base_px * CPAD + q4 * 8];

  floatx4 acc[2][2][NF];
  #pragma unroll
  for (int rr = 0; rr < 2; ++rr)
    #pragma unroll
    for (int mf = 0; mf < 2; ++mf)
      #pragma unroll
      for (int nf = 0; nf < NF; ++nf) acc[rr][mf][nf] = (floatx4){0.f, 0.f, 0.f, 0.f};

  #pragma unroll
  for (int dh = 0; dh < 3; ++dh) {
    #pragma unroll
    for (int dw = 0; dw < 3; ++dw) {
      #pragma unroll
      for (int kc = 0; kc < KC; ++kc) {
        const int tap = dh * 3 + dw;
        short8 bg[NF];
        #pragma unroll
        for (int nf = 0; nf < NF; ++nf)
          bg[nf] = *(const short8*)&wf[((((tap * KC + kc) * NG) + wave_n * NF + nf) * 64 + lane) * 8];
        #pragma unroll
        for (int rr = 0; rr < 2; ++rr) {
          short8 a[2];
          #pragma unroll
          for (int mf = 0; mf < 2; ++mf)
            a[mf] = *(const short8*)&abase[((rr + dh) * 66 + dw + mf * 16) * CPAD + kc * 32];
          #pragma unroll
          for (int mf = 0; mf < 2; ++mf)
            #pragma unroll
            for (int nf = 0; nf < NF; ++nf)
              acc[rr][mf][nf] = __builtin_amdgcn_mfma_f32_16x16x32_bf16(a[mf], bg[nf], acc[rr][mf][nf], 0, 0, 0);
        }
      }
    }
  }

  float bv[NF], sa[NF], qa[NF];
  #pragma unroll
  for (int nf = 0; nf < NF; ++nf) {
    bv[nf] = bias[wave_n * (COUT / 2) + nf * 16 + j15];
    sa[nf] = 0.f; qa[nf] = 0.f;
  }
  #pragma unroll
  for (int rr = 0; rr < 2; ++rr) {
    const size_t orow = ((size_t)(b * 256 + (h0 + rr)) * 256 + w0);
    #pragma unroll
    for (int nf = 0; nf < NF; ++nf) {
      const int ch = wave_n * (COUT / 2) + nf * 16 + j15;
      #pragma unroll
      for (int mf = 0; mf < 2; ++mf)
        #pragma unroll
        for (int r4 = 0; r4 < 4; ++r4) {
          float y = acc[rr][mf][nf][r4] + bv[nf];
          sa[nf] += y; qa[nf] += y * y;
          if constexpr (WRITE_OUT) {
            const int p = wave_m * 32 + mf * 16 + q4 * 4 + r4;
            out[(orow + p) * COUT + ch] = f2bf(y);
          }
        }
    }
  }

  __syncthreads();
  float* red = (float*)lds;
  #pragma unroll
  for (int nf = 0; nf < NF; ++nf) {
    float s = sa[nf], q = qa[nf];
    s += __shfl_xor(s, 16); s += __shfl_xor(s, 32);
    q += __shfl_xor(q, 16); q += __shfl_xor(q, 32);
    if (lane < 16) {
      red[(wv * NF + nf) * 16 + lane] = s;
      red[4 * NF * 16 + (wv * NF + nf) * 16 + lane] = q;
    }
  }
  __syncthreads();
  if (tid < COUT) {
    const int wn = tid / (COUT / 2), rr = tid % (COUT / 2);
    const int nf = rr >> 4, li = rr & 15;
    float s = red[(wn * NF + nf) * 16 + li] + red[((wn + 2) * NF + nf) * 16 + li];
    float q = red[4 * NF * 16 + (wn * NF + nf) * 16 + li] +
              red[4 * NF * 16 + ((wn + 2) * NF + nf) * 16 + li];
    const int sl = lin & (NSLOT - 1);
    atomicAdd(&totals_out[((size_t)sl * 2 + 0) * COUT + tid], s);
    atomicAdd(&totals_out[((size_t)sl * 2 + 1) * COUT + tid], q);
  }
}

// ---- fused outputs: patches (blocks 0..13) + encode (blocks 14..21) -------
__global__ __launch_bounds__(256) void outputs_kernel(
    const float* __restrict__ img, const int* __restrict__ axy,
    const int* __restrict__ pxy, const int* __restrict__ nxy,
    const unsigned short* __restrict__ y2, const float* __restrict__ wgt,
    const float* __restrict__ bias,
    const float* __restrict__ totals2, const float* __restrict__ g2,
    const float* __restrict__ b2v,
    const float* __restrict__ totals3, const float* __restrict__ g3,
    const float* __restrict__ b3v,
    float* __restrict__ out)
{
  if (blockIdx.x < 14) {
    const int i = blockIdx.x * 256 + threadIdx.x;
    if (i >= 3 * BATCH * 3 * 49) return;
    const int arr = i / 1176, r = i % 1176;
    const int b = r / 147, q = r % 147;
    const int c = q / 49, s = q % 49;
    const int ph = s / 7, pw = s % 7;
    const int* xy = (arr == 0) ? axy : ((arr == 1) ? pxy : nxy);
    const int x = xy[(b * 32 + 31) * 2 + 0];
    const int y = xy[(b * 32 + 31) * 2 + 1];
    out[i] = img[((size_t)(b * 3 + c) * HH + (x - 3 + ph)) * WW + (y - 3 + pw)];
  } else {
    const int b = blockIdx.x - 14;         // 0..7
    const int x = nxy[(b * 32 + 31) * 2 + 0];
    const int y = nxy[(b * 32 + 31) * 2 + 1];
    __shared__ float sc2[2][64], sc3[2][128];
    __shared__ float act[576];             // k = ci*9 + dh*3 + dw
    if (threadIdx.x < 64) {
      float s = 0.f, q = 0.f;
      for (int i = 0; i < NSLOT; ++i) {
        s += totals2[((size_t)i * 2 + 0) * 64 + threadIdx.x];
        q += totals2[((size_t)i * 2 + 1) * 64 + threadIdx.x];
      }
      const float mean = s / BN_N;
      const float var = q / BN_N - mean * mean;
      const float rstd = rsqrtf(var + 1e-5f);
      const float sc = g2[threadIdx.x] * rstd;
      sc2[0][threadIdx.x] = sc;
      sc2[1][threadIdx.x] = b2v[threadIdx.x] - mean * sc;
    } else if (threadIdx.x >= 128) {
      const int c = threadIdx.x - 128;
      float s = 0.f, q = 0.f;
      for (int i = 0; i < NSLOT; ++i) {
        s += totals3[((size_t)i * 2 + 0) * 128 + c];
        q += totals3[((size_t)i * 2 + 1) * 128 + c];
      }
      const float mean = s / BN_N;
      const float var = q / BN_N - mean * mean;
      const float rstd = rsqrtf(var + 1e-5f);
      const float sc = g3[c] * rstd;
      sc3[0][c] = sc;
      sc3[1][c] = b3v[c] - mean * sc;
    }
    __syncthreads();
    for (int t = threadIdx.x; t < 576; t += 256) {
      const int ci = t / 9, tap = t - ci * 9;
      const int dh = tap / 3, dw = tap - dh * 3;
      float v = bf2f(y2[((size_t)(b * 256 + (x + dh - 1)) * 256 + (y + dw - 1)) * 64 + ci]);
      v = v * sc2[0][ci] + sc2[1][ci];
      act[t] = fmaxf(v, 0.01f * v);
    }
    __syncthreads();
    if (threadIdx.x < 128) {
      const int co = threadIdx.x;
      float acc = bias[co];
      const float4* w4 = (const float4*)(wgt + (size_t)co * 576);
      #pragma unroll 9
      for (int kk = 0; kk < 144; ++kk) {
        const float4 wv = w4[kk];
        acc = fmaf(wv.x, act[4 * kk + 0], acc);
        acc = fmaf(wv.y, act[4 * kk + 1], acc);
        acc = fmaf(wv.z, act[4 * kk + 2], acc);
        acc = fmaf(wv.w, act[4 * kk + 3], acc);
      }
      const float yv = acc * sc3[0][co] + sc3[1][co];
      out[3528 + b * 128 + co] = fmaxf(yv, 0.01f * yv);
    }
  }
}

extern "C" void kernel_launch(void* const* d_in, const int* in_sizes, int n_in,
                              void* d_out, int out_size, void* d_ws, size_t ws_size,
                              hipStream_t stream)
{
  const float* image = (const float*)d_in[0];
  const int* axy = (const int*)d_in[1];
  const int* pxy = (const int*)d_in[2];
  const int* nxy = (const int*)d_in[3];
  const float* c1w = (const float*)d_in[4];
  const float* c1b = (const float*)d_in[5];
  const float* g1 = (const float*)d_in[6];
  const float* b1 = (const float*)d_in[7];
  const float* c2w = (const float*)d_in[8];
  const float* c2b = (const float*)d_in[9];
  const float* g2 = (const float*)d_in[10];
  const float* b2 = (const float*)d_in[11];
  const float* c3w = (const float*)d_in[12];
  const float* c3b = (const float*)d_in[13];
  const float* g3 = (const float*)d_in[14];
  const float* b3 = (const float*)d_in[15];
  float* out = (float*)d_out;

  // workspace layout (~101 MB)
  unsigned short* zb1 = (unsigned short*)d_ws;            // raw y1, 16.78M bf16
  unsigned short* zb2 = zb1 + (size_t)8 * 32 * HWSZ;      // raw y2, 33.55M bf16
  unsigned short* wf2 = zb2 + (size_t)8 * 64 * HWSZ;      // 18432
  unsigned short* wf3 = wf2 + 18432;                      // 73728
  float* totals1 = (float*)(wf3 + 73728);                 // 64*2*32  = 4096
  float* totals2 = totals1 + (size_t)NSLOT * 2 * 32;      // 64*2*64  = 8192
  float* totals3 = totals2 + (size_t)NSLOT * 2 * 64;      // 64*2*128 = 16384

  // zero the 64-slot stat accumulators (28672 floats)
  hipMemsetAsync(totals1, 0, (size_t)NSLOT * 2 * (32 + 64 + 128) * sizeof(float),
                 stream);

  // conv1 via MFMA (blocks 0..4095) + wf2/wf3 prep (blocks 4096..4455)
  conv1_mfma<<<4456, 256, 0, stream>>>(
      image, c1w, c1b, zb1, totals1, c2w, c3w, wf2, wf3);

  // layer 2: 32 -> 64 (MFMA; bn1 folded inline; raw y2 out + slot stats)
  conv_mfma<32, 64, true, 2><<<4096, 256, 0, stream>>>(
      zb1, wf2, c2b, totals1, g1, b1, zb2, totals2);

  // layer 3: 64 -> 128 (MFMA; bn2 folded inline; stats only)
  conv_mfma<64, 128, false, 2><<<4096, 256, 0, stream>>>(
      zb2, wf3, c3b, totals2, g2, b2, nullptr, totals3);

  // outputs: patches (0..13) + per-batch encode (14..21), bn folds inline
  outputs_kernel<<<22, 256, 0, stream>>>(image, axy, pxy, nxy, zb2, c3w, c3b,
                                         totals2, g2, b2, totals3, g3, b3, out);
}

// Round 17
// 238.702 us; speedup vs baseline: 1.8250x; 1.0105x over previous
//
#include <hip/hip_runtime.h>
#include <math.h>

#define HH 256
#define WW 256
#define BATCH 8
#define HWSZ 65536
#define BN_N 524288.0f  // BATCH*HWSZ
#define NSLOT 64        // stat-slot spreading factor

typedef __attribute__((ext_vector_type(8))) short short8;
typedef __attribute__((ext_vector_type(4))) float floatx4;

// round-half-up bf16 pack: 2 VALU ops, max err 0.5 ulp
__device__ __forceinline__ unsigned short f2bf(float f) {
  union { float f; unsigned int u; } v; v.f = f;
  return (unsigned short)((v.u + 0x8000u) >> 16);
}
// pack two fp32 -> bf16x2 (lo=a, hi=d): 5 VALU ops
__device__ __forceinline__ unsigned int pack2bf(float a, float d) {
  union { float f; unsigned int u; } va, vd; va.f = a; vd.f = d;
  return ((va.u + 0x8000u) >> 16) | ((vd.u + 0x8000u) & 0xffff0000u);
}
__device__ __forceinline__ float bf2f(unsigned short u) {
  union { unsigned int u; float f; } v; v.u = ((unsigned int)u) << 16;
  return v.f;
}

// ---- conv1 as im2col MFMA (blocks 0..4095) + wf2/wf3 prep (4096..4455) ----
__global__ __launch_bounds__(256) void conv1_mfma(
    const float* __restrict__ img, const float* __restrict__ w1,
    const float* __restrict__ bias, unsigned short* __restrict__ out,
    float* __restrict__ totals1,
    const float* __restrict__ w2, const float* __restrict__ w3,
    unsigned short* __restrict__ wf2, unsigned short* __restrict__ wf3)
{
  const int lin = blockIdx.x;
  if (lin >= 4096) {  // ---- prep path: 360 blocks cover 92160 elems ----
    int idx = (lin - 4096) * 256 + threadIdx.x;
    if (idx < 18432) {  // conv2: CIN=32, COUT=64, KC=1, NG=4
      const int j = idx & 7;
      const int lane = (idx >> 3) & 63;
      int rest = idx >> 9;
      const int ng = rest % 4;
      const int tap = rest / 4;
      const int cout = ng * 16 + (lane & 15);
      const int cin = ((lane >> 4) << 3) + j;
      wf2[idx] = f2bf(w2[((size_t)cout * 32 + cin) * 9 + tap]);
    } else {            // conv3: CIN=64, COUT=128, KC=2, NG=8
      idx -= 18432;
      if (idx >= 73728) return;
      const int j = idx & 7;
      const int lane = (idx >> 3) & 63;
      int rest = idx >> 9;
      const int ng = rest % 8; rest /= 8;
      const int kc = rest & 1;
      const int tap = rest >> 1;
      const int cout = ng * 16 + (lane & 15);
      const int cin = kc * 32 + ((lane >> 4) << 3) + j;
      wf3[idx] = f2bf(w3[((size_t)cout * 64 + cin) * 9 + tap]);
    }
    return;
  }

  const int tid = threadIdx.x, lane = tid & 63, wv = tid >> 6;
  const int wave_m = wv >> 1, wave_n = wv & 1;
  const int xcd = lin & 7, slot = lin >> 3;
  const int b = slot >> 6;
  const int rem = slot & 63;
  const int h0 = ((xcd << 4) + (rem >> 2)) * 2;
  const int w0 = (rem & 3) * 64;

  __shared__ __align__(16) unsigned short simg[4 * 66 * 4];  // [row][px][3ch+pad]
  __shared__ __align__(16) unsigned short swf[2 * 64 * 8];   // conv1 B-frags
  __shared__ float red2[2][4][16];                           // [s|q][wv][li]

  for (int t = tid; t < (4 * 66 * 4) / 2; t += 256)
    ((unsigned int*)simg)[t] = 0u;
  {
    const int t0 = tid * 4;
    #pragma unroll
    for (int u = 0; u < 4; ++u) {
      const int idx = t0 + u;
      const int j = idx & 7, l8 = (idx >> 3) & 63, nt = idx >> 9;
      const int k = ((l8 >> 4) << 3) + j;
      const int cout = nt * 16 + (l8 & 15);
      swf[idx] = (k < 27) ? f2bf(w1[cout * 27 + k]) : (unsigned short)0;
    }
  }
  __syncthreads();
  for (int t = tid; t < 792; t += 256) {
    const int ci = t / 264, r2 = t - ci * 264;
    const int r = r2 / 66, px = r2 - r * 66;
    const int hi = h0 + r - 1, wi = w0 + px - 1;
    if ((unsigned)hi < 256u && (unsigned)wi < 256u)
      simg[(r * 66 + px) * 4 + ci] =
          f2bf(img[((size_t)(b * 3 + ci) * 256 + hi) * 256 + wi]);
  }
  __syncthreads();

  const int j15 = lane & 15, q4 = lane >> 4;
  int off[8];
  #pragma unroll
  for (int j = 0; j < 8; ++j) {
    const int k = q4 * 8 + j;
    const int ci = k / 9, tap = k - ci * 9;
    const int dh = tap / 3, dw = tap - dh * 3;
    off[j] = (dh * 66 + dw) * 4 + ci;
  }
  const int base_px = wave_m * 32 + j15;
  const short8 bg = *(const short8*)&swf[(wave_n * 64 + lane) * 8];

  floatx4 acc[2][2];
  #pragma unroll
  for (int rr = 0; rr < 2; ++rr)
    #pragma unroll
    for (int mf = 0; mf < 2; ++mf) {
      acc[rr][mf] = (floatx4){0.f, 0.f, 0.f, 0.f};
      union { short8 v; unsigned short e[8]; } a;
      const int ab = (rr * 66 + base_px + mf * 16) * 4;
      #pragma unroll
      for (int j = 0; j < 8; ++j) a.e[j] = simg[ab + off[j]];
      acc[rr][mf] = __builtin_amdgcn_mfma_f32_16x16x32_bf16(a.v, bg, acc[rr][mf], 0, 0, 0);
    }

  float sa = 0.f, qa = 0.f;
  const float bv = bias[wave_n * 16 + j15];
  #pragma unroll
  for (int rr = 0; rr < 2; ++rr) {
    const size_t orow = ((size_t)(b * 256 + (h0 + rr)) * 256 + w0);
    #pragma unroll
    for (int mf = 0; mf < 2; ++mf)
      #pragma unroll
      for (int r4 = 0; r4 < 4; ++r4) {
        float y = acc[rr][mf][r4] + bv;
        sa += y; qa += y * y;
        const int p = wave_m * 32 + mf * 16 + q4 * 4 + r4;
        out[(orow + p) * 32 + wave_n * 16 + j15] = f2bf(y);
      }
  }
  sa += __shfl_xor(sa, 16); sa += __shfl_xor(sa, 32);
  qa += __shfl_xor(qa, 16); qa += __shfl_xor(qa, 32);
  if (lane < 16) { red2[0][wv][lane] = sa; red2[1][wv][lane] = qa; }
  __syncthreads();
  if (tid < 64) {
    const int c = tid >> 1, jj = tid & 1;
    const int wn = c >> 4, li = c & 15;
    const float r = red2[jj][wn][li] + red2[jj][wn + 2][li];
    atomicAdd(&totals1[(((size_t)(lin & (NSLOT - 1)) * 2 + jj)) * 32 + c], r);
  }
}

// ---- MFMA conv: 64px x R ROWS x COUT per block, PADDED affine LDS ---------
// R=4 for conv2 (144 MFMA/barrier, staging redundancy 1.5x), R=2 for conv3
// (proven config). Parallel BN fold; fixed-ck staging; XCD-aware decode;
// 64-way-spread atomic stats.
template<int CIN, int COUT, int R, bool WRITE_OUT, int MINW>
__global__ __launch_bounds__(256, MINW) void conv_mfma(
    const unsigned short* __restrict__ in, const unsigned short* __restrict__ wf,
    const float* __restrict__ bias,
    const float* __restrict__ totals_in, const float* __restrict__ gamma_in,
    const float* __restrict__ beta_in,
    unsigned short* __restrict__ out, float* __restrict__ totals_out)
{
  constexpr int KC = CIN / 32;
  constexpr int NG = COUT / 16;
  constexpr int NF = COUT / 32;
  constexpr int CH8 = CIN / 8;
  constexpr int CH8_LOG = (CH8 == 4) ? 2 : 3;
  constexpr int CPAD = CIN + 8;
  constexpr int GRP = 256 / CIN;        // fold groups
  constexpr int SPG = NSLOT / GRP;      // slots per group
  constexpr int ROWS = R + 2;           // staged rows
  constexpr int HT8 = (256 / R) / 8;    // h-tiles per XCD per batch
  constexpr int SLB = (256 / R) / 2;    // slots per batch (x4 w-tiles / 8 xcd)

  const int tid = threadIdx.x, lane = tid & 63, wv = tid >> 6;
  const int wave_m = wv >> 1, wave_n = wv & 1;

  const int lin = blockIdx.x;
  const int xcd = lin & 7, slot = lin >> 3;
  const int b = slot / SLB;
  const int rem = slot % SLB;
  const int h0 = (xcd * HT8 + (rem >> 2)) * R;
  const int w0 = (rem & 3) * 64;
  const size_t inb = (size_t)b * HWSZ * CIN;

  __shared__ __align__(16) unsigned short lds[ROWS * 66 * CPAD];
  __shared__ __align__(16) float scsh[2][CIN];

  // parallel BN fold: 256 threads cover NSLOT slots in GRP groups
  {
    const int c = tid % CIN, g = tid / CIN;
    float ps = 0.f, pq = 0.f;
    #pragma unroll
    for (int i = 0; i < SPG; ++i) {
      const int sl = g * SPG + i;
      ps += totals_in[((size_t)sl * 2 + 0) * CIN + c];
      pq += totals_in[((size_t)sl * 2 + 1) * CIN + c];
    }
    float* pf = (float*)lds;  // [2][GRP][CIN] partials (staging overwrites later)
    pf[(0 * GRP + g) * CIN + c] = ps;
    pf[(1 * GRP + g) * CIN + c] = pq;
    __syncthreads();
    if (tid < CIN) {
      float s = 0.f, q = 0.f;
      #pragma unroll
      for (int g2 = 0; g2 < GRP; ++g2) {
        s += pf[(0 * GRP + g2) * CIN + tid];
        q += pf[(1 * GRP + g2) * CIN + tid];
      }
      const float mean = s / BN_N;
      const float var = q / BN_N - mean * mean;
      const float rstd = rsqrtf(var + 1e-5f);
      const float sc = gamma_in[tid] * rstd;
      scsh[0][tid] = sc;
      scsh[1][tid] = beta_in[tid] - mean * sc;
    }
    __syncthreads();
  }

  // staging: fixed ck per thread; scale/shift regs loaded ONCE
  {
    const int ck = tid & (CH8 - 1);
    const float4 s0 = *(const float4*)&scsh[0][ck * 8];
    const float4 s1 = *(const float4*)&scsh[0][ck * 8 + 4];
    const float4 t0 = *(const float4*)&scsh[1][ck * 8];
    const float4 t1 = *(const float4*)&scsh[1][ck * 8 + 4];
    const float scs[8] = {s0.x, s0.y, s0.z, s0.w, s1.x, s1.y, s1.z, s1.w};
    const float shs[8] = {t0.x, t0.y, t0.z, t0.w, t1.x, t1.y, t1.z, t1.w};
    for (int rpx = tid >> CH8_LOG; rpx < ROWS * 66; rpx += 256 >> CH8_LOG) {
      const int r = rpx / 66, px = rpx - r * 66;
      const int hi = h0 + r - 1, wi = w0 - 1 + px;
      uint4 v = make_uint4(0u, 0u, 0u, 0u);
      if ((unsigned)hi < 256u && (unsigned)wi < 256u) {
        uint4 raw = *(const uint4*)&in[inb + ((size_t)hi * 256 + wi) * CIN + ck * 8];
        unsigned int* u = (unsigned int*)&raw;
        unsigned int* o = (unsigned int*)&v;
        #pragma unroll
        for (int p = 0; p < 4; ++p) {
          float a = bf2f((unsigned short)(u[p] & 0xffff));
          float d = bf2f((unsigned short)(u[p] >> 16));
          float ya = a * scs[2 * p] + shs[2 * p];
          float yd = d * scs[2 * p + 1] + shs[2 * p + 1];
          ya = fmaxf(ya, 0.01f * ya);
          yd = fmaxf(yd, 0.01f * yd);
          o[p] = pack2bf(ya, yd);
        }
      }
      *(uint4*)&lds[rpx * CPAD + ck * 8] = v;
    }
  }
  __syncthreads();

  const int j15 = lane & 15, q4 = lane >> 4;
  const int base_px = wave_m * 32 + j15;
  const unsigned short* abase = &lds[base_px * CPAD + q4 * 8];

  floatx4 acc[R][2][NF];
  #pragma unroll
  for (int rr = 0; rr < R; ++rr)
    #pragma unroll
    for (int mf = 0; mf < 2; ++mf)
      #pragma unroll
      for (int nf = 0; nf < NF; ++nf) acc[rr][mf][nf] = (floatx4){0.f, 0.f, 0.f, 0.f};

  #pragma unroll
  for (int dh = 0; dh < 3; ++dh) {
    #pragma unroll
    for (int dw = 0; dw < 3; ++dw) {
      #pragma unroll
      for (int kc = 0; kc < KC; ++kc) {
        const int tap = dh * 3 + dw;
        short8 bg[NF];
        #pragma unroll
        for (int nf = 0; nf < NF; ++nf)
          bg[nf] = *(const short8*)&wf[((((tap * KC + kc) * NG) + wave_n * NF + nf) * 64 + lane) * 8];
        #pragma unroll
        for (int rr = 0; rr < R; ++rr) {
          short8 a[2];
          #pragma unroll
          for (int mf = 0; mf < 2; ++mf)
            a[mf] = *(const short8*)&abase[((rr + dh) * 66 + dw + mf * 16) * CPAD + kc * 32];
          #pragma unroll
          for (int mf = 0; mf < 2; ++mf)
            #pragma unroll
            for (int nf = 0; nf < NF; ++nf)
              acc[rr][mf][nf] = __builtin_amdgcn_mfma_f32_16x16x32_bf16(a[mf], bg[nf], acc[rr][mf][nf], 0, 0, 0);
        }
      }
    }
  }

  float bv[NF], sa[NF], qa[NF];
  #pragma unroll
  for (int nf = 0; nf < NF; ++nf) {
    bv[nf] = bias[wave_n * (COUT / 2) + nf * 16 + j15];
    sa[nf] = 0.f; qa[nf] = 0.f;
  }
  #pragma unroll
  for (int rr = 0; rr < R; ++rr) {
    const size_t orow = ((size_t)(b * 256 + (h0 + rr)) * 256 + w0);
    #pragma unroll
    for (int nf = 0; nf < NF; ++nf) {
      const int ch = wave_n * (COUT / 2) + nf * 16 + j15;
      #pragma unroll
      for (int mf = 0; mf < 2; ++mf)
        #pragma unroll
        for (int r4 = 0; r4 < 4; ++r4) {
          float y = acc[rr][mf][nf][r4] + bv[nf];
          sa[nf] += y; qa[nf] += y * y;
          if constexpr (WRITE_OUT) {
            const int p = wave_m * 32 + mf * 16 + q4 * 4 + r4;
            out[(orow + p) * COUT + ch] = f2bf(y);
          }
        }
    }
  }

  __syncthreads();
  float* red = (float*)lds;
  #pragma unroll
  for (int nf = 0; nf < NF; ++nf) {
    float s = sa[nf], q = qa[nf];
    s += __shfl_xor(s, 16); s += __shfl_xor(s, 32);
    q += __shfl_xor(q, 16); q += __shfl_xor(q, 32);
    if (lane < 16) {
      red[(wv * NF + nf) * 16 + lane] = s;
      red[4 * NF * 16 + (wv * NF + nf) * 16 + lane] = q;
    }
  }
  __syncthreads();
  if (tid < COUT) {
    const int wn = tid / (COUT / 2), rr = tid % (COUT / 2);
    const int nf = rr >> 4, li = rr & 15;
    float s = red[(wn * NF + nf) * 16 + li] + red[((wn + 2) * NF + nf) * 16 + li];
    float q = red[4 * NF * 16 + (wn * NF + nf) * 16 + li] +
              red[4 * NF * 16 + ((wn + 2) * NF + nf) * 16 + li];
    const int sl = lin & (NSLOT - 1);
    atomicAdd(&totals_out[((size_t)sl * 2 + 0) * COUT + tid], s);
    atomicAdd(&totals_out[((size_t)sl * 2 + 1) * COUT + tid], q);
  }
}

// ---- fused outputs: patches (blocks 0..13) + encode (blocks 14..21) -------
__global__ __launch_bounds__(256) void outputs_kernel(
    const float* __restrict__ img, const int* __restrict__ axy,
    const int* __restrict__ pxy, const int* __restrict__ nxy,
    const unsigned short* __restrict__ y2, const float* __restrict__ wgt,
    const float* __restrict__ bias,
    const float* __restrict__ totals2, const float* __restrict__ g2,
    const float* __restrict__ b2v,
    const float* __restrict__ totals3, const float* __restrict__ g3,
    const float* __restrict__ b3v,
    float* __restrict__ out)
{
  if (blockIdx.x < 14) {
    const int i = blockIdx.x * 256 + threadIdx.x;
    if (i >= 3 * BATCH * 3 * 49) return;
    const int arr = i / 1176, r = i % 1176;
    const int b = r / 147, q = r % 147;
    const int c = q / 49, s = q % 49;
    const int ph = s / 7, pw = s % 7;
    const int* xy = (arr == 0) ? axy : ((arr == 1) ? pxy : nxy);
    const int x = xy[(b * 32 + 31) * 2 + 0];
    const int y = xy[(b * 32 + 31) * 2 + 1];
    out[i] = img[((size_t)(b * 3 + c) * HH + (x - 3 + ph)) * WW + (y - 3 + pw)];
  } else {
    const int b = blockIdx.x - 14;         // 0..7
    const int x = nxy[(b * 32 + 31) * 2 + 0];
    const int y = nxy[(b * 32 + 31) * 2 + 1];
    __shared__ float sc2[2][64], sc3[2][128];
    __shared__ float act[576];             // k = ci*9 + dh*3 + dw
    if (threadIdx.x < 64) {
      float s = 0.f, q = 0.f;
      for (int i = 0; i < NSLOT; ++i) {
        s += totals2[((size_t)i * 2 + 0) * 64 + threadIdx.x];
        q += totals2[((size_t)i * 2 + 1) * 64 + threadIdx.x];
      }
      const float mean = s / BN_N;
      const float var = q / BN_N - mean * mean;
      const float rstd = rsqrtf(var + 1e-5f);
      const float sc = g2[threadIdx.x] * rstd;
      sc2[0][threadIdx.x] = sc;
      sc2[1][threadIdx.x] = b2v[threadIdx.x] - mean * sc;
    } else if (threadIdx.x >= 128) {
      const int c = threadIdx.x - 128;
      float s = 0.f, q = 0.f;
      for (int i = 0; i < NSLOT; ++i) {
        s += totals3[((size_t)i * 2 + 0) * 128 + c];
        q += totals3[((size_t)i * 2 + 1) * 128 + c];
      }
      const float mean = s / BN_N;
      const float var = q / BN_N - mean * mean;
      const float rstd = rsqrtf(var + 1e-5f);
      const float sc = g3[c] * rstd;
      sc3[0][c] = sc;
      sc3[1][c] = b3v[c] - mean * sc;
    }
    __syncthreads();
    for (int t = threadIdx.x; t < 576; t += 256) {
      const int ci = t / 9, tap = t - ci * 9;
      const int dh = tap / 3, dw = tap - dh * 3;
      float v = bf2f(y2[((size_t)(b * 256 + (x + dh - 1)) * 256 + (y + dw - 1)) * 64 + ci]);
      v = v * sc2[0][ci] + sc2[1][ci];
      act[t] = fmaxf(v, 0.01f * v);
    }
    __syncthreads();
    if (threadIdx.x < 128) {
      const int co = threadIdx.x;
      float acc = bias[co];
      const float4* w4 = (const float4*)(wgt + (size_t)co * 576);
      #pragma unroll 9
      for (int kk = 0; kk < 144; ++kk) {
        const float4 wv = w4[kk];
        acc = fmaf(wv.x, act[4 * kk + 0], acc);
        acc = fmaf(wv.y, act[4 * kk + 1], acc);
        acc = fmaf(wv.z, act[4 * kk + 2], acc);
        acc = fmaf(wv.w, act[4 * kk + 3], acc);
      }
      const float yv = acc * sc3[0][co] + sc3[1][co];
      out[3528 + b * 128 + co] = fmaxf(yv, 0.01f * yv);
    }
  }
}

extern "C" void kernel_launch(void* const* d_in, const int* in_sizes, int n_in,
                              void* d_out, int out_size, void* d_ws, size_t ws_size,
                              hipStream_t stream)
{
  const float* image = (const float*)d_in[0];
  const int* axy = (const int*)d_in[1];
  const int* pxy = (const int*)d_in[2];
  const int* nxy = (const int*)d_in[3];
  const float* c1w = (const float*)d_in[4];
  const float* c1b = (const float*)d_in[5];
  const float* g1 = (const float*)d_in[6];
  const float* b1 = (const float*)d_in[7];
  const float* c2w = (const float*)d_in[8];
  const float* c2b = (const float*)d_in[9];
  const float* g2 = (const float*)d_in[10];
  const float* b2 = (const float*)d_in[11];
  const float* c3w = (const float*)d_in[12];
  const float* c3b = (const float*)d_in[13];
  const float* g3 = (const float*)d_in[14];
  const float* b3 = (const float*)d_in[15];
  float* out = (float*)d_out;

  // workspace layout (~101 MB)
  unsigned short* zb1 = (unsigned short*)d_ws;            // raw y1, 16.78M bf16
  unsigned short* zb2 = zb1 + (size_t)8 * 32 * HWSZ;      // raw y2, 33.55M bf16
  unsigned short* wf2 = zb2 + (size_t)8 * 64 * HWSZ;      // 18432
  unsigned short* wf3 = wf2 + 18432;                      // 73728
  float* totals1 = (float*)(wf3 + 73728);                 // 64*2*32  = 4096
  float* totals2 = totals1 + (size_t)NSLOT * 2 * 32;      // 64*2*64  = 8192
  float* totals3 = totals2 + (size_t)NSLOT * 2 * 64;      // 64*2*128 = 16384

  // zero the 64-slot stat accumulators (28672 floats)
  hipMemsetAsync(totals1, 0, (size_t)NSLOT * 2 * (32 + 64 + 128) * sizeof(float),
                 stream);

  // conv1 via MFMA (blocks 0..4095) + wf2/wf3 prep (blocks 4096..4455)
  conv1_mfma<<<4456, 256, 0, stream>>>(
      image, c1w, c1b, zb1, totals1, c2w, c3w, wf2, wf3);

  // layer 2: 32 -> 64 (MFMA, R=4: 144 MFMA/barrier; bn1 folded inline)
  conv_mfma<32, 64, 4, true, 2><<<2048, 256, 0, stream>>>(
      zb1, wf2, c2b, totals1, g1, b1, zb2, totals2);

  // layer 3: 64 -> 128 (MFMA, R=2 proven config; bn2 folded inline)
  conv_mfma<64, 128, 2, false, 2><<<4096, 256, 0, stream>>>(
      zb2, wf3, c3b, totals2, g2, b2, nullptr, totals3);

  // outputs: patches (0..13) + per-batch encode (14..21), bn folds inline
  outputs_kernel<<<22, 256, 0, stream>>>(image, axy, pxy, nxy, zb2, c3w, c3b,
                                         totals2, g2, b2, totals3, g3, b3, out);
}